// Round 3
// baseline (5073.429 us; speedup 1.0000x reference)
//
#include <hip/hip_runtime.h>

#define T 512
#define HDIM 128
#define G4 512
#define LOUT 128
#define KEXT 639
#define KPAD 640

typedef _Float16 half8 __attribute__((ext_vector_type(8)));
typedef _Float16 half2t __attribute__((ext_vector_type(2)));
typedef float f32x4 __attribute__((ext_vector_type(4)));

__device__ __forceinline__ int clampT(int v) { return v < 0 ? 0 : (v > T ? T : v); }

__device__ __forceinline__ float fast_sigmoid(float x) {
  return __builtin_amdgcn_rcpf(1.f + __builtin_amdgcn_exp2f(x * -1.44269504f));
}
__device__ __forceinline__ float fast_tanh(float x) {
  float ax = __builtin_fabsf(x);
  float e = __builtin_amdgcn_exp2f(ax * -2.88539008f);
  float t = (1.f - e) * __builtin_amdgcn_rcpf(1.f + e);
  return __builtin_copysignf(t, x);
}
__device__ __forceinline__ half8 load8f(const float* p) {
  float4 q0 = *(const float4*)p;
  float4 q1 = *(const float4*)(p + 4);
  half8 v;
  v[0] = (_Float16)q0.x; v[1] = (_Float16)q0.y; v[2] = (_Float16)q0.z; v[3] = (_Float16)q0.w;
  v[4] = (_Float16)q1.x; v[5] = (_Float16)q1.y; v[6] = (_Float16)q1.z; v[7] = (_Float16)q1.w;
  return v;
}

// ---------------------------------------------------------------------------
// Kernel A: persistent 2-layer LSTM, encoder (masked) + decoder (teacher forced)
// 16 WGs x 512 threads; each WG owns 16 batch rows; weights live in VGPRs as
// fp16 MFMA B-fragments. Writes Vext[b][0..638][128] (fp16) and Hfin[b][128].
// ---------------------------------------------------------------------------
__global__ __launch_bounds__(512, 1)
void lstm_kernel(const float* __restrict__ x, const float* __restrict__ y,
                 const int* __restrict__ lengths,
                 const float* __restrict__ Wih0, const float* __restrict__ Whh0,
                 const float* __restrict__ bih0, const float* __restrict__ bhh0,
                 const float* __restrict__ Wih1, const float* __restrict__ Whh1,
                 const float* __restrict__ bih1, const float* __restrict__ bhh1,
                 _Float16* __restrict__ Vext, _Float16* __restrict__ Hfin)
{
  const int tid  = threadIdx.x;
  const int wave = tid >> 6;
  const int lane = tid & 63;
  const int fr   = lane & 15;   // MFMA fragment row/col index
  const int fg   = lane >> 4;   // MFMA k-group
  const int b0   = blockIdx.x * 16;

  __shared__ float    gates[G4][20];     // [gate-col n][batch(+pad)]
  __shared__ _Float16 h1buf[16][136];    // [batch][H(+pad)]
  __shared__ _Float16 h2buf[16][136];
  __shared__ float    xst[16][3];
  __shared__ int      lens_s[16];

  // ---- load weight fragments (B operand: B[k][n] = W[n][k]) ----
  half8 bh0[4][4], bi1[4][4], bh1[4][4];
#pragma unroll
  for (int nt = 0; nt < 4; ++nt) {
    const int n = wave * 64 + nt * 16 + fr;
#pragma unroll
    for (int kf = 0; kf < 4; ++kf) {
      const int k = kf * 32 + fg * 8;
      bh0[nt][kf] = load8f(Whh0 + n * HDIM + k);
      bi1[nt][kf] = load8f(Wih1 + n * HDIM + k);
      bh1[nt][kf] = load8f(Whh1 + n * HDIM + k);
    }
  }

  // ---- per-thread cell-update assignment: unit cu, batch quad cbq ----
  const int cu  = tid & 127;
  const int cbq = tid >> 7;
  float b0r[4], b1r[4], w0r[4][3];
#pragma unroll
  for (int g = 0; g < 4; ++g) {
    const int n = g * 128 + cu;
    b0r[g] = bih0[n] + bhh0[n];
    b1r[g] = bih1[n] + bhh1[n];
    w0r[g][0] = Wih0[n * 3 + 0];
    w0r[g][1] = Wih0[n * 3 + 1];
    w0r[g][2] = Wih0[n * 3 + 2];
  }
  float c1r[4] = {0.f, 0.f, 0.f, 0.f};
  float c2r[4] = {0.f, 0.f, 0.f, 0.f};

  if (tid < 16) lens_s[tid] = clampT(lengths[b0 + tid]);  // clamp: no data-driven hang
  for (int it = tid; it < 16 * 136; it += 512) {
    (&h1buf[0][0])[it] = (_Float16)0.f;
    (&h2buf[0][0])[it] = (_Float16)0.f;
  }
  __syncthreads();

  int mylen[4];
#pragma unroll
  for (int bb = 0; bb < 4; ++bb) mylen[bb] = lens_s[cbq * 4 + bb];
  int maxlen = 0, minlen = T;
  for (int i = 0; i < 16; ++i) {
    maxlen = max(maxlen, lens_s[i]);
    minlen = min(minlen, lens_s[i]);
  }

  // zero-fill lstm_out rows past each sequence length
  {
    const int zbi = tid >> 5;
    const int zu  = (tid & 31) * 4;
    const int zlen = lens_s[zbi];
    for (int t = minlen; t < T; ++t) {
      if (t >= zlen) {
        _Float16* dst = Vext + ((size_t)(b0 + zbi) * KEXT + t) * HDIM + zu;
        dst[0] = (_Float16)0.f; dst[1] = (_Float16)0.f;
        dst[2] = (_Float16)0.f; dst[3] = (_Float16)0.f;
      }
    }
  }

  auto step = [&](int t, bool enc) {
    // stage x_t / y_t
    if (tid < 48) {
      const int sbi = tid / 3, sj = tid - sbi * 3;
      xst[sbi][sj] = enc ? x[((size_t)(b0 + sbi) * T + t) * 3 + sj]
                         : y[((size_t)(b0 + sbi) * LOUT + t) * 3 + sj];
    }
    // ---- layer 0 matmul: gates = h1 @ Whh0^T ----
    half8 af[4];
#pragma unroll
    for (int kf = 0; kf < 4; ++kf)
      af[kf] = *(const half8*)&h1buf[fr][kf * 32 + fg * 8];
#pragma unroll
    for (int nt = 0; nt < 4; ++nt) {
      f32x4 a = {0.f, 0.f, 0.f, 0.f};
#pragma unroll
      for (int kf = 0; kf < 4; ++kf)
        a = __builtin_amdgcn_mfma_f32_16x16x32_f16(af[kf], bh0[nt][kf], a, 0, 0, 0);
      *(f32x4*)&gates[wave * 64 + nt * 16 + fr][fg * 4] = a;
    }
    __syncthreads();
    // ---- layer 0 cell update ----
    {
      const f32x4 gI = *(const f32x4*)&gates[cu][cbq * 4];
      const f32x4 gF = *(const f32x4*)&gates[128 + cu][cbq * 4];
      const f32x4 gG = *(const f32x4*)&gates[256 + cu][cbq * 4];
      const f32x4 gO = *(const f32x4*)&gates[384 + cu][cbq * 4];
#pragma unroll
      for (int bb = 0; bb < 4; ++bb) {
        const int bidx = cbq * 4 + bb;
        const float x0 = xst[bidx][0], x1 = xst[bidx][1], x2 = xst[bidx][2];
        const float gi = gI[bb] + b0r[0] + x0 * w0r[0][0] + x1 * w0r[0][1] + x2 * w0r[0][2];
        const float gf = gF[bb] + b0r[1] + x0 * w0r[1][0] + x1 * w0r[1][1] + x2 * w0r[1][2];
        const float gg = gG[bb] + b0r[2] + x0 * w0r[2][0] + x1 * w0r[2][1] + x2 * w0r[2][2];
        const float go = gO[bb] + b0r[3] + x0 * w0r[3][0] + x1 * w0r[3][1] + x2 * w0r[3][2];
        const float c = fast_sigmoid(gf) * c1r[bb] + fast_sigmoid(gi) * fast_tanh(gg);
        const float h = fast_sigmoid(go) * fast_tanh(c);
        const bool  v = (!enc) || (t < mylen[bb]);
        if (v) { c1r[bb] = c; h1buf[bidx][cu] = (_Float16)h; }
      }
    }
    __syncthreads();
    // ---- layer 1 matmul: gates = h1n @ Wih1^T + h2 @ Whh1^T ----
    half8 af1[8];
#pragma unroll
    for (int kf = 0; kf < 4; ++kf) {
      af1[kf]     = *(const half8*)&h1buf[fr][kf * 32 + fg * 8];
      af1[4 + kf] = *(const half8*)&h2buf[fr][kf * 32 + fg * 8];
    }
#pragma unroll
    for (int nt = 0; nt < 4; ++nt) {
      f32x4 a = {0.f, 0.f, 0.f, 0.f};
#pragma unroll
      for (int kf = 0; kf < 4; ++kf)
        a = __builtin_amdgcn_mfma_f32_16x16x32_f16(af1[kf], bi1[nt][kf], a, 0, 0, 0);
#pragma unroll
      for (int kf = 0; kf < 4; ++kf)
        a = __builtin_amdgcn_mfma_f32_16x16x32_f16(af1[4 + kf], bh1[nt][kf], a, 0, 0, 0);
      *(f32x4*)&gates[wave * 64 + nt * 16 + fr][fg * 4] = a;
    }
    __syncthreads();
    // ---- layer 1 cell update + Vext store ----
    {
      const int orow = enc ? t : (T + t);
      const f32x4 gI = *(const f32x4*)&gates[cu][cbq * 4];
      const f32x4 gF = *(const f32x4*)&gates[128 + cu][cbq * 4];
      const f32x4 gG = *(const f32x4*)&gates[256 + cu][cbq * 4];
      const f32x4 gO = *(const f32x4*)&gates[384 + cu][cbq * 4];
#pragma unroll
      for (int bb = 0; bb < 4; ++bb) {
        const int bidx = cbq * 4 + bb;
        const float gi = gI[bb] + b1r[0];
        const float gf = gF[bb] + b1r[1];
        const float gg = gG[bb] + b1r[2];
        const float go = gO[bb] + b1r[3];
        const float c = fast_sigmoid(gf) * c2r[bb] + fast_sigmoid(gi) * fast_tanh(gg);
        const float h = fast_sigmoid(go) * fast_tanh(c);
        const bool  v = (!enc) || (t < mylen[bb]);
        if (v) { c2r[bb] = c; h2buf[bidx][cu] = (_Float16)h; }
        Vext[((size_t)(b0 + bidx) * KEXT + orow) * HDIM + cu] =
            v ? (_Float16)h : (_Float16)0.f;
      }
    }
    __syncthreads();
  };

  for (int t = 0; t < maxlen; ++t) step(t, true);
  // final encoder h2 -> query source for p=0
  for (int it = tid; it < 16 * HDIM; it += 512)
    Hfin[(size_t)(b0 + (it >> 7)) * HDIM + (it & 127)] = h2buf[it >> 7][it & 127];
  __syncthreads();
  for (int i = 0; i < LOUT - 1; ++i) step(i, false);
}

// ---------------------------------------------------------------------------
// Kernel B: tA[b][h][k] = tanh(Vext[b][k] @ Wa^T + bWa)  (fp16, k-major)
//           tq[b][p][h] = tanh(Q_p @ Ua^T + bUa)         (fp16)
// One WG per batch element, 4 waves, MFMA.
// ---------------------------------------------------------------------------
__global__ __launch_bounds__(256, 1)
void proj_kernel(const _Float16* __restrict__ Vext, const _Float16* __restrict__ Hfin,
                 const float* __restrict__ Wa, const float* __restrict__ bWa,
                 const float* __restrict__ Ua, const float* __restrict__ bUa,
                 _Float16* __restrict__ tA, _Float16* __restrict__ tq)
{
  const int b = blockIdx.x;
  const int tid = threadIdx.x;
  const int wave = tid >> 6, lane = tid & 63;
  const int fr = lane & 15, fg = lane >> 4;
  __shared__ _Float16 tile[4][128][24];

  half8 bf[8][4];
  float bias_r[8];
#pragma unroll
  for (int nt = 0; nt < 8; ++nt) {
    const int ho = nt * 16 + fr;
    bias_r[nt] = bWa[ho];
#pragma unroll
    for (int kf = 0; kf < 4; ++kf)
      bf[nt][kf] = load8f(Wa + ho * HDIM + kf * 32 + fg * 8);
  }

  for (int r = 0; r < 10; ++r) {
    const int mt = r * 4 + wave;
    int row = mt * 16 + fr;
    if (row > KEXT - 1) row = KEXT - 1;   // pad row duplicates last key (masked later)
    const _Float16* src = Vext + ((size_t)b * KEXT + row) * HDIM;
    half8 af[4];
#pragma unroll
    for (int kf = 0; kf < 4; ++kf) af[kf] = *(const half8*)(src + kf * 32 + fg * 8);
#pragma unroll
    for (int nt = 0; nt < 8; ++nt) {
      f32x4 a = {0.f, 0.f, 0.f, 0.f};
#pragma unroll
      for (int kf = 0; kf < 4; ++kf)
        a = __builtin_amdgcn_mfma_f32_16x16x32_f16(af[kf], bf[nt][kf], a, 0, 0, 0);
#pragma unroll
      for (int j = 0; j < 4; ++j)
        tile[wave][nt * 16 + fr][fg * 4 + j] = (_Float16)fast_tanh(a[j] + bias_r[nt]);
    }
    __syncthreads();
    for (int it = tid; it < 4 * 128; it += 256) {
      const int w2 = it >> 7, ho = it & 127;
      const half8 v0 = *(const half8*)&tile[w2][ho][0];
      const half8 v1 = *(const half8*)&tile[w2][ho][8];
      _Float16* dst = tA + ((size_t)b * HDIM + ho) * KPAD + (r * 4 + w2) * 16;
      *(half8*)dst = v0;
      *(half8*)(dst + 8) = v1;
    }
    __syncthreads();
  }

  // ---- query projection ----
#pragma unroll
  for (int nt = 0; nt < 8; ++nt) {
    const int ho = nt * 16 + fr;
    bias_r[nt] = bUa[ho];
#pragma unroll
    for (int kf = 0; kf < 4; ++kf)
      bf[nt][kf] = load8f(Ua + ho * HDIM + kf * 32 + fg * 8);
  }
  for (int r = 0; r < 2; ++r) {
    const int mt = r * 4 + wave;
    const int prow = mt * 16 + fr;   // query index for A-row
    const _Float16* src = (prow == 0)
        ? (Hfin + (size_t)b * HDIM)
        : (Vext + ((size_t)b * KEXT + 511 + prow) * HDIM);  // d_{p-1}
    half8 af[4];
#pragma unroll
    for (int kf = 0; kf < 4; ++kf) af[kf] = *(const half8*)(src + kf * 32 + fg * 8);
#pragma unroll
    for (int nt = 0; nt < 8; ++nt) {
      f32x4 a = {0.f, 0.f, 0.f, 0.f};
#pragma unroll
      for (int kf = 0; kf < 4; ++kf)
        a = __builtin_amdgcn_mfma_f32_16x16x32_f16(af[kf], bf[nt][kf], a, 0, 0, 0);
#pragma unroll
      for (int j = 0; j < 4; ++j) {
        const int p = mt * 16 + fg * 4 + j;
        tq[((size_t)b * LOUT + p) * HDIM + nt * 16 + fr] = (_Float16)fast_tanh(a[j] + bias_r[nt]);
      }
    }
  }
}

// ---------------------------------------------------------------------------
// Kernel C: all 128 attention steps in parallel.
// score(p,k) = sum_h Va[h] * tanh(A_kh + q_ph), via tanh addition identity.
// grid = (B, 4 p-blocks), 512 threads, each wave owns 4 queries.
// ---------------------------------------------------------------------------
__global__ __launch_bounds__(512, 1)
void attn_kernel(const _Float16* __restrict__ Vext,
                 const _Float16* __restrict__ tA,
                 const _Float16* __restrict__ tq,
                 const float* __restrict__ Va,
                 const int* __restrict__ lengths,
                 const float* __restrict__ fc1w, const float* __restrict__ fc1b,
                 const float* __restrict__ fc2w, const float* __restrict__ fc2b,
                 float* __restrict__ out)
{
  const int b = blockIdx.x;
  const int p0 = blockIdx.y * 32;
  const int tid = threadIdx.x, wave = tid >> 6, lane = tid & 63;
  __shared__ float qs[32][HDIM];
  __shared__ float vas[HDIM];
  __shared__ float sc[32][KPAD];
  __shared__ float ctxs[32][HDIM];
  __shared__ float rbuf[32][36];

  for (int it = tid; it < 32 * HDIM; it += 512)
    qs[it >> 7][it & 127] = (float)tq[((size_t)b * LOUT + p0 + (it >> 7)) * HDIM + (it & 127)];
  if (tid < HDIM) vas[tid] = Va[tid];
  const int len = clampT(lengths[b]);
  __syncthreads();

  for (int pp = 0; pp < 4; ++pp) {
    const int prow = wave * 4 + pp;
    const int p = p0 + prow;
    // ---- scores ----
    for (int kc = 0; kc < 5; ++kc) {
      const int k0 = kc * 128 + lane * 2;
      const _Float16* ap = tA + (size_t)b * HDIM * KPAD + k0;
      float acc0 = 0.f, acc1 = 0.f;
#pragma unroll 4
      for (int h = 0; h < HDIM; ++h) {
        const half2t a = *(const half2t*)(ap + (size_t)h * KPAD);
        const float tqv = qs[prow][h];
        const float va = vas[h];
        const float a0 = (float)a[0], a1 = (float)a[1];
        const float t0 = (a0 + tqv) * __builtin_amdgcn_rcpf(fmaf(a0, tqv, 1.f));
        const float t1 = (a1 + tqv) * __builtin_amdgcn_rcpf(fmaf(a1, tqv, 1.f));
        acc0 = fmaf(va, t0, acc0);
        acc1 = fmaf(va, t1, acc1);
      }
      const int k1 = k0 + 1;
      const bool v0 = (k0 < T) ? ((k0 < len) && (k0 == 0 || k0 > p)) : ((k0 - T) < p);
      const bool v1 = (k1 < T) ? ((k1 < len) && (k1 > p)) : ((k1 - T) < p);
      float2 sv;
      sv.x = v0 ? acc0 : -__builtin_inff();
      sv.y = v1 ? acc1 : -__builtin_inff();
      *(float2*)&sc[prow][k0] = sv;
    }
    __syncthreads();
    // ---- softmax over the 639 extended keys (wave-local row) ----
    float m = -__builtin_inff();
    for (int k = lane; k < KPAD; k += 64) m = fmaxf(m, sc[prow][k]);
#pragma unroll
    for (int off = 32; off; off >>= 1) m = fmaxf(m, __shfl_xor(m, off, 64));
    float ssum = 0.f;
    for (int k = lane; k < KPAD; k += 64) {
      const float e = __builtin_amdgcn_exp2f((sc[prow][k] - m) * 1.44269504f);
      sc[prow][k] = e;
      ssum += e;
    }
#pragma unroll
    for (int off = 32; off; off >>= 1) ssum += __shfl_xor(ssum, off, 64);
    const float inv = __builtin_amdgcn_rcpf(ssum);
    __syncthreads();
    // ---- context: ctx[h] = sum_k w_k * Vext[b][k][h] ----
    const int h0 = lane * 2;
    float ca = 0.f, cb = 0.f;
    const _Float16* vp = Vext + (size_t)b * KEXT * HDIM + h0;
#pragma unroll 4
    for (int k = 0; k < KEXT; ++k) {
      const float wgt = sc[prow][k];
      const half2t v = *(const half2t*)(vp + (size_t)k * HDIM);
      ca = fmaf(wgt, (float)v[0], ca);
      cb = fmaf(wgt, (float)v[1], cb);
    }
    ctxs[prow][h0] = ca * inv;
    ctxs[prow][h0 + 1] = cb * inv;
    __syncthreads();
    // ---- head: relu(ctx @ fc1^T + b1) @ fc2^T + b2 ----
    if (lane < 32) {
      float a = fc1b[lane];
      const float* wrow = fc1w + lane * HDIM;
      for (int h = 0; h < HDIM; ++h) a = fmaf(ctxs[prow][h], wrow[h], a);
      rbuf[prow][lane] = fmaxf(a, 0.f);
    }
    __syncthreads();
    if (lane < 2) {
      float a = fc2b[lane];
      const float* wrow = fc2w + lane * 32;
#pragma unroll
      for (int o = 0; o < 32; ++o) a = fmaf(rbuf[prow][o], wrow[o], a);
      out[((size_t)b * LOUT + p) * 2 + lane] = a;
    }
    __syncthreads();
  }
}

// ---------------------------------------------------------------------------
extern "C" void kernel_launch(void* const* d_in, const int* in_sizes, int n_in,
                              void* d_out, int out_size, void* d_ws, size_t ws_size,
                              hipStream_t stream)
{
  const float* x     = (const float*)d_in[0];
  const float* y     = (const float*)d_in[1];
  // d_in[2]: masks (redundant with lengths)
  const int* lengths = (const int*)d_in[3];
  const float* Wih0  = (const float*)d_in[4];
  const float* Whh0  = (const float*)d_in[5];
  const float* bih0  = (const float*)d_in[6];
  const float* bhh0  = (const float*)d_in[7];
  const float* Wih1  = (const float*)d_in[8];
  const float* Whh1  = (const float*)d_in[9];
  const float* bih1  = (const float*)d_in[10];
  const float* bhh1  = (const float*)d_in[11];
  const float* Wa    = (const float*)d_in[12];
  const float* bWa   = (const float*)d_in[13];
  const float* Ua    = (const float*)d_in[14];
  const float* bUa   = (const float*)d_in[15];
  const float* Va    = (const float*)d_in[16];
  // d_in[17]: bVa — constant shift, softmax-invariant, unused
  const float* fc1w  = (const float*)d_in[18];
  const float* fc1b  = (const float*)d_in[19];
  const float* fc2w  = (const float*)d_in[20];
  const float* fc2b  = (const float*)d_in[21];

  char* wsp = (char*)d_ws;
  _Float16* Vext = (_Float16*)(wsp);              // 256*639*128*2  = 41,877,504
  _Float16* Hfin = (_Float16*)(wsp + 41877504);   // 256*128*2      =     65,536
  _Float16* tA   = (_Float16*)(wsp + 41943040);   // 256*128*640*2  = 41,943,040
  _Float16* tq   = (_Float16*)(wsp + 83886080);   // 256*128*128*2  =  8,388,608
  (void)in_sizes; (void)n_in; (void)out_size; (void)ws_size;

  lstm_kernel<<<16, 512, 0, stream>>>(x, y, lengths, Wih0, Whh0, bih0, bhh0,
                                      Wih1, Whh1, bih1, bhh1, Vext, Hfin);
  proj_kernel<<<256, 256, 0, stream>>>(Vext, Hfin, Wa, bWa, Ua, bUa, tA, tq);
  attn_kernel<<<dim3(256, 4), 512, 0, stream>>>(Vext, tA, tq, Va, lengths,
                                                fc1w, fc1b, fc2w, fc2b,
                                                (float*)d_out);
}

// Round 4
// 4396.558 us; speedup vs baseline: 1.1540x; 1.1540x over previous
//
#include <hip/hip_runtime.h>

#define T 512
#define HDIM 128
#define LOUT 128
#define KEXT 639
#define KPAD 640

typedef _Float16 half8 __attribute__((ext_vector_type(8)));
typedef _Float16 half2t __attribute__((ext_vector_type(2)));
typedef float f32x4 __attribute__((ext_vector_type(4)));

__device__ __forceinline__ int clampT(int v) { return v < 0 ? 0 : (v > T ? T : v); }

__device__ __forceinline__ float fast_sigmoid(float x) {
  return __builtin_amdgcn_rcpf(1.f + __builtin_amdgcn_exp2f(x * -1.44269504f));
}
__device__ __forceinline__ float fast_tanh(float x) {
  float ax = __builtin_fabsf(x);
  float e = __builtin_amdgcn_exp2f(ax * -2.88539008f);
  float t = (1.f - e) * __builtin_amdgcn_rcpf(1.f + e);
  return __builtin_copysignf(t, x);
}
__device__ __forceinline__ half8 load8f(const float* p) {
  float4 q0 = *(const float4*)p;
  float4 q1 = *(const float4*)(p + 4);
  half8 v;
  v[0] = (_Float16)q0.x; v[1] = (_Float16)q0.y; v[2] = (_Float16)q0.z; v[3] = (_Float16)q0.w;
  v[4] = (_Float16)q1.x; v[5] = (_Float16)q1.y; v[6] = (_Float16)q1.z; v[7] = (_Float16)q1.w;
  return v;
}

// ---------------------------------------------------------------------------
// Kernel A: persistent 2-layer LSTM. 16 WGs x 512 threads, 16 batch rows/WG.
// Wave w owns hidden units u = w*16 + (lane&15) across ALL FOUR gate blocks
// (cols n = g*128+u), so the MFMA accumulator fragment IS the cell-update
// layout: no gates LDS round-trip, cell state in registers, 2 barriers/step.
// Whh0+Whh1 resident in VGPRs (128); Wih1 staged in LDS (128 KiB).
// ---------------------------------------------------------------------------
__global__ __launch_bounds__(512, 2)
void lstm_kernel(const float* __restrict__ x, const float* __restrict__ y,
                 const int* __restrict__ lengths,
                 const float* __restrict__ Wih0, const float* __restrict__ Whh0,
                 const float* __restrict__ bih0, const float* __restrict__ bhh0,
                 const float* __restrict__ Wih1, const float* __restrict__ Whh1,
                 const float* __restrict__ bih1, const float* __restrict__ bhh1,
                 _Float16* __restrict__ Vext, _Float16* __restrict__ Hfin)
{
  const int tid  = threadIdx.x;
  const int w    = tid >> 6;
  const int lane = tid & 63;
  const int fr   = lane & 15;
  const int fg   = lane >> 4;
  const int b0   = blockIdx.x * 16;
  const int u    = w * 16 + fr;          // hidden unit owned by this thread

  __shared__ _Float16 w1lds[8][4][4][4][16][8];  // Wih1 frags [w][g][kf][fg][fr][e]
  __shared__ _Float16 h1buf[2][16][136];
  __shared__ _Float16 h2buf[2][16][136];
  __shared__ float    xst[2][16][4];
  __shared__ int      lens_s[16];

  // resident Whh0 / Whh1 fragments + per-unit constants
  half8 bh0r[4][4], bh1r[4][4];
  float w0r[4][3], b0r[4], b1r[4];
#pragma unroll
  for (int g = 0; g < 4; ++g) {
    const int n = g * 128 + u;
    b0r[g] = bih0[n] + bhh0[n];
    b1r[g] = bih1[n] + bhh1[n];
    w0r[g][0] = Wih0[n * 3 + 0];
    w0r[g][1] = Wih0[n * 3 + 1];
    w0r[g][2] = Wih0[n * 3 + 2];
#pragma unroll
    for (int kf = 0; kf < 4; ++kf) {
      bh0r[g][kf] = load8f(Whh0 + n * HDIM + kf * 32 + fg * 8);
      bh1r[g][kf] = load8f(Whh1 + n * HDIM + kf * 32 + fg * 8);
    }
  }

  if (tid < 16) lens_s[tid] = clampT(lengths[b0 + tid]);
  for (int it = tid; it < 2 * 16 * 136; it += 512) {
    (&h1buf[0][0][0])[it] = (_Float16)0.f;
    (&h2buf[0][0][0])[it] = (_Float16)0.f;
  }
  // stage Wih1 fragments into LDS (one time)
  for (int c = tid; c < 8192; c += 512) {
    const int n = c >> 4, k8 = c & 15;
    half8 v = load8f(Wih1 + n * HDIM + k8 * 8);
    *(half8*)&w1lds[(n >> 4) & 7][n >> 7][k8 >> 2][k8 & 3][n & 15][0] = v;
  }
  __syncthreads();

  int mylen[4];
#pragma unroll
  for (int j = 0; j < 4; ++j) mylen[j] = lens_s[fg * 4 + j];
  int maxlen = 0, minlen = T;
  for (int i = 0; i < 16; ++i) {
    maxlen = max(maxlen, lens_s[i]);
    minlen = min(minlen, lens_s[i]);
  }

  // zero-fill lstm_out rows past each sequence length
  {
    const int zbi = tid >> 5, zu = (tid & 31) * 4;
    const int zlen = lens_s[zbi];
    for (int t = minlen; t < T; ++t) {
      if (t >= zlen) {
        _Float16* dst = Vext + ((size_t)(b0 + zbi) * KEXT + t) * HDIM + zu;
        dst[0] = (_Float16)0.f; dst[1] = (_Float16)0.f;
        dst[2] = (_Float16)0.f; dst[3] = (_Float16)0.f;
      }
    }
  }

  const int S = maxlen + LOUT - 1;   // total timeline steps

  // prologue: stage inputs for steps 0 and 1
  if (tid < 48) {
    const int sbi = tid / 3, sj = tid - sbi * 3;
    xst[0][sbi][sj] = (0 < maxlen) ? x[((size_t)(b0 + sbi) * T + 0) * 3 + sj]
                                   : y[((size_t)(b0 + sbi) * LOUT + (0 - maxlen)) * 3 + sj];
    xst[1][sbi][sj] = (1 < maxlen) ? x[((size_t)(b0 + sbi) * T + 1) * 3 + sj]
                                   : y[((size_t)(b0 + sbi) * LOUT + (1 - maxlen)) * 3 + sj];
  }
  __syncthreads();

  float c1r[4] = {0.f, 0.f, 0.f, 0.f}, c2r[4] = {0.f, 0.f, 0.f, 0.f};
  _Float16 h1h[4] = {(_Float16)0.f, (_Float16)0.f, (_Float16)0.f, (_Float16)0.f};
  _Float16 h2h[4] = {(_Float16)0.f, (_Float16)0.f, (_Float16)0.f, (_Float16)0.f};

  // cell0(0): h1(-1)=0 so gates = b0 + Wih0*x(0)
#pragma unroll
  for (int j = 0; j < 4; ++j) {
    const int bidx = fg * 4 + j;
    const float x0 = xst[0][bidx][0], x1 = xst[0][bidx][1], x2 = xst[0][bidx][2];
    float gv[4];
#pragma unroll
    for (int g = 0; g < 4; ++g)
      gv[g] = b0r[g] + x0 * w0r[g][0] + x1 * w0r[g][1] + x2 * w0r[g][2];
    const float c = fast_sigmoid(gv[0]) * fast_tanh(gv[2]);
    const float h = fast_sigmoid(gv[3]) * fast_tanh(c);
    const bool v = (0 >= maxlen) || (0 < mylen[j]);
    if (v) { c1r[j] = c; h1h[j] = (_Float16)h; }
    h1buf[0][bidx][u] = h1h[j];
  }
  __syncthreads();

  half8 h1f[4];
  for (int s = 0; s < S; ++s) {
    const int p = s & 1;
    // ---- deferred Vext / Hfin stores for step s-1 (drain hides under MFMA) ----
    if (s > 0) {
      const int prow = s - 1;
      const int row = (prow < maxlen) ? prow : (T + prow - maxlen);
#pragma unroll
      for (int j = 0; j < 4; ++j) {
        const bool v = (prow >= maxlen) || (prow < mylen[j]);
        if (v) Vext[((size_t)(b0 + fg * 4 + j) * KEXT + row) * HDIM + u] = h2h[j];
      }
      if (prow == maxlen - 1) {
#pragma unroll
        for (int j = 0; j < 4; ++j)
          Hfin[(size_t)(b0 + fg * 4 + j) * HDIM + u] = h2h[j];
      }
    }
    // ---- prefetch input(s+2) into registers ----
    float xr = 0.f; int sbi = 0, sj = 0;
    const bool havex = (tid < 48) && (s + 2 < S);
    if (havex) {
      sbi = tid / 3; sj = tid - sbi * 3;
      const int k = s + 2;
      xr = (k < maxlen) ? x[((size_t)(b0 + sbi) * T + k) * 3 + sj]
                        : y[((size_t)(b0 + sbi) * LOUT + (k - maxlen)) * 3 + sj];
    }
    // ---- MFMA: G1(s) = h1(s)@Wih1^T + h2(s-1)@Whh1^T + b1 ----
#pragma unroll
    for (int kf = 0; kf < 4; ++kf)
      h1f[kf] = *(const half8*)&h1buf[p][fr][kf * 32 + fg * 8];
    half8 h2f[4];
#pragma unroll
    for (int kf = 0; kf < 4; ++kf)
      h2f[kf] = *(const half8*)&h2buf[p ^ 1][fr][kf * 32 + fg * 8];
    f32x4 acc[4];
#pragma unroll
    for (int g = 0; g < 4; ++g) {
      f32x4 a = {b1r[g], b1r[g], b1r[g], b1r[g]};
#pragma unroll
      for (int kf = 0; kf < 4; ++kf)
        a = __builtin_amdgcn_mfma_f32_16x16x32_f16(
                h1f[kf], *(const half8*)&w1lds[w][g][kf][fg][fr][0], a, 0, 0, 0);
#pragma unroll
      for (int kf = 0; kf < 4; ++kf)
        a = __builtin_amdgcn_mfma_f32_16x16x32_f16(h2f[kf], bh1r[g][kf], a, 0, 0, 0);
      acc[g] = a;
    }
    // ---- cell1(s) (gates live in acc; no LDS round-trip) ----
#pragma unroll
    for (int j = 0; j < 4; ++j) {
      const float gi = acc[0][j], gf = acc[1][j], gg = acc[2][j], go = acc[3][j];
      const float c = fast_sigmoid(gf) * c2r[j] + fast_sigmoid(gi) * fast_tanh(gg);
      const float h = fast_sigmoid(go) * fast_tanh(c);
      const bool v = (s >= maxlen) || (s < mylen[j]);
      if (v) { c2r[j] = c; h2h[j] = (_Float16)h; }
      h2buf[p][fg * 4 + j][u] = h2h[j];
    }
    __syncthreads();                    // B1
    if (s + 1 < S) {
      // ---- MFMA: G0(s+1) = h1(s)@Whh0^T  (h1f registers reused across B1) ----
#pragma unroll
      for (int g = 0; g < 4; ++g) {
        f32x4 a = {0.f, 0.f, 0.f, 0.f};
#pragma unroll
        for (int kf = 0; kf < 4; ++kf)
          a = __builtin_amdgcn_mfma_f32_16x16x32_f16(h1f[kf], bh0r[g][kf], a, 0, 0, 0);
        acc[g] = a;
      }
      if (havex) xst[p][sbi][sj] = xr;  // stage input(s+2) (read at iter s+1)
      const int p1 = p ^ 1;
      // ---- cell0(s+1) ----
#pragma unroll
      for (int j = 0; j < 4; ++j) {
        const int bidx = fg * 4 + j;
        const float x0 = xst[p1][bidx][0], x1 = xst[p1][bidx][1], x2 = xst[p1][bidx][2];
        const float gi = acc[0][j] + b0r[0] + x0 * w0r[0][0] + x1 * w0r[0][1] + x2 * w0r[0][2];
        const float gf = acc[1][j] + b0r[1] + x0 * w0r[1][0] + x1 * w0r[1][1] + x2 * w0r[1][2];
        const float gg = acc[2][j] + b0r[2] + x0 * w0r[2][0] + x1 * w0r[2][1] + x2 * w0r[2][2];
        const float go = acc[3][j] + b0r[3] + x0 * w0r[3][0] + x1 * w0r[3][1] + x2 * w0r[3][2];
        const float c = fast_sigmoid(gf) * c1r[j] + fast_sigmoid(gi) * fast_tanh(gg);
        const float h = fast_sigmoid(go) * fast_tanh(c);
        const bool v = (s + 1 >= maxlen) || (s + 1 < mylen[j]);
        if (v) { c1r[j] = c; h1h[j] = (_Float16)h; }
        h1buf[p1][bidx][u] = h1h[j];
      }
    }
    __syncthreads();                    // B2
  }
  // final deferred store: step S-1 -> decoder row 638
  {
    const int row = T + (S - 1) - maxlen;
#pragma unroll
    for (int j = 0; j < 4; ++j)
      Vext[((size_t)(b0 + fg * 4 + j) * KEXT + row) * HDIM + u] = h2h[j];
  }
}

// ---------------------------------------------------------------------------
// Kernel B: tA[b][h][k] = tanh(Vext[b][k] @ Wa^T + bWa)  (fp16, k-major)
//           tq[b][p][h] = tanh(Q_p @ Ua^T + bUa)         (fp16)
// ---------------------------------------------------------------------------
__global__ __launch_bounds__(256, 1)
void proj_kernel(const _Float16* __restrict__ Vext, const _Float16* __restrict__ Hfin,
                 const float* __restrict__ Wa, const float* __restrict__ bWa,
                 const float* __restrict__ Ua, const float* __restrict__ bUa,
                 _Float16* __restrict__ tA, _Float16* __restrict__ tq)
{
  const int b = blockIdx.x;
  const int tid = threadIdx.x;
  const int wave = tid >> 6, lane = tid & 63;
  const int fr = lane & 15, fg = lane >> 4;
  __shared__ _Float16 tile[4][128][24];

  half8 bf[8][4];
  float bias_r[8];
#pragma unroll
  for (int nt = 0; nt < 8; ++nt) {
    const int ho = nt * 16 + fr;
    bias_r[nt] = bWa[ho];
#pragma unroll
    for (int kf = 0; kf < 4; ++kf)
      bf[nt][kf] = load8f(Wa + ho * HDIM + kf * 32 + fg * 8);
  }

  for (int r = 0; r < 10; ++r) {
    const int mt = r * 4 + wave;
    int row = mt * 16 + fr;
    if (row > KEXT - 1) row = KEXT - 1;
    const _Float16* src = Vext + ((size_t)b * KEXT + row) * HDIM;
    half8 af[4];
#pragma unroll
    for (int kf = 0; kf < 4; ++kf) af[kf] = *(const half8*)(src + kf * 32 + fg * 8);
#pragma unroll
    for (int nt = 0; nt < 8; ++nt) {
      f32x4 a = {0.f, 0.f, 0.f, 0.f};
#pragma unroll
      for (int kf = 0; kf < 4; ++kf)
        a = __builtin_amdgcn_mfma_f32_16x16x32_f16(af[kf], bf[nt][kf], a, 0, 0, 0);
#pragma unroll
      for (int j = 0; j < 4; ++j)
        tile[wave][nt * 16 + fr][fg * 4 + j] = (_Float16)fast_tanh(a[j] + bias_r[nt]);
    }
    __syncthreads();
    for (int it = tid; it < 4 * 128; it += 256) {
      const int w2 = it >> 7, ho = it & 127;
      const half8 v0 = *(const half8*)&tile[w2][ho][0];
      const half8 v1 = *(const half8*)&tile[w2][ho][8];
      _Float16* dst = tA + ((size_t)b * HDIM + ho) * KPAD + (r * 4 + w2) * 16;
      *(half8*)dst = v0;
      *(half8*)(dst + 8) = v1;
    }
    __syncthreads();
  }

#pragma unroll
  for (int nt = 0; nt < 8; ++nt) {
    const int ho = nt * 16 + fr;
    bias_r[nt] = bUa[ho];
#pragma unroll
    for (int kf = 0; kf < 4; ++kf)
      bf[nt][kf] = load8f(Ua + ho * HDIM + kf * 32 + fg * 8);
  }
  for (int r = 0; r < 2; ++r) {
    const int mt = r * 4 + wave;
    const int prow = mt * 16 + fr;
    const _Float16* src = (prow == 0)
        ? (Hfin + (size_t)b * HDIM)
        : (Vext + ((size_t)b * KEXT + 511 + prow) * HDIM);
    half8 af[4];
#pragma unroll
    for (int kf = 0; kf < 4; ++kf) af[kf] = *(const half8*)(src + kf * 32 + fg * 8);
#pragma unroll
    for (int nt = 0; nt < 8; ++nt) {
      f32x4 a = {0.f, 0.f, 0.f, 0.f};
#pragma unroll
      for (int kf = 0; kf < 4; ++kf)
        a = __builtin_amdgcn_mfma_f32_16x16x32_f16(af[kf], bf[nt][kf], a, 0, 0, 0);
#pragma unroll
      for (int j = 0; j < 4; ++j) {
        const int pq = mt * 16 + fg * 4 + j;
        tq[((size_t)b * LOUT + pq) * HDIM + nt * 16 + fr] = (_Float16)fast_tanh(a[j] + bias_r[nt]);
      }
    }
  }
}

// ---------------------------------------------------------------------------
// Kernel C: all 128 attention steps in parallel, with tA/Vext chunks staged
// in LDS (shared by all 8 waves) instead of per-wave strided global streams.
// grid = (B, 4 p-blocks), 512 threads, each wave owns 4 queries.
// ---------------------------------------------------------------------------
__global__ __launch_bounds__(512, 1)
void attn_kernel(const _Float16* __restrict__ Vext,
                 const _Float16* __restrict__ tA,
                 const _Float16* __restrict__ tq,
                 const float* __restrict__ Va,
                 const int* __restrict__ lengths,
                 const float* __restrict__ fc1w, const float* __restrict__ fc1b,
                 const float* __restrict__ fc2w, const float* __restrict__ fc2b,
                 float* __restrict__ out)
{
  const int b = blockIdx.x;
  const int p0 = blockIdx.y * 32;
  const int tid = threadIdx.x, wv = tid >> 6, lane = tid & 63;

  __shared__ float    sc[32][KPAD];     // 80 KiB
  __shared__ _Float16 stg[128][136];    // 34 KiB chunk staging (tA / Vext)
  __shared__ _Float16 qs[32][136];      // 8.5 KiB
  __shared__ float    vas[HDIM];
  __shared__ float    ctxs[32][HDIM];   // 16 KiB
  __shared__ _Float16 f1[32][136];      // 8.5 KiB fc1 weights (fp16)

  for (int it = tid; it < 32 * HDIM; it += 512)
    qs[it >> 7][it & 127] = tq[((size_t)b * LOUT + p0 + (it >> 7)) * HDIM + (it & 127)];
  if (tid < HDIM) vas[tid] = Va[tid];
  for (int it = tid; it < 32 * HDIM; it += 512)
    f1[it >> 7][it & 127] = (_Float16)fc1w[it];
  const int len = clampT(lengths[b]);
  const float fb   = (lane < 32) ? fc1b[lane] : 0.f;
  const float w2a  = (lane < 32) ? fc2w[lane] : 0.f;
  const float w2b  = (lane < 32) ? fc2w[32 + lane] : 0.f;
  const float f2b0 = fc2b[0], f2b1 = fc2b[1];
  __syncthreads();

  // ---- scores, kc-chunked ----
  for (int kc = 0; kc < 5; ++kc) {
    __syncthreads();
    for (int it = tid; it < 2048; it += 512) {
      const int hh = it >> 4, ks = it & 15;
      *(half8*)&stg[hh][ks * 8] =
          *(const half8*)(tA + ((size_t)b * HDIM + hh) * KPAD + kc * 128 + ks * 8);
    }
    __syncthreads();
#pragma unroll
    for (int pp = 0; pp < 4; ++pp) {
      const int prow = wv * 4 + pp;
      const int p = p0 + prow;
      const int k0 = kc * 128 + lane * 2;
      float acc0 = 0.f, acc1 = 0.f;
#pragma unroll 4
      for (int h = 0; h < HDIM; ++h) {
        const half2t a = *(const half2t*)&stg[h][lane * 2];
        const float tqv = (float)qs[prow][h];
        const float va = vas[h];
        const float a0 = (float)a[0], a1 = (float)a[1];
        const float t0 = (a0 + tqv) * __builtin_amdgcn_rcpf(fmaf(a0, tqv, 1.f));
        const float t1 = (a1 + tqv) * __builtin_amdgcn_rcpf(fmaf(a1, tqv, 1.f));
        acc0 = fmaf(va, t0, acc0);
        acc1 = fmaf(va, t1, acc1);
      }
      const int k1 = k0 + 1;
      const bool v0 = (k0 < T) ? ((k0 < len) && (k0 == 0 || k0 > p)) : ((k0 - T) < p);
      const bool v1 = (k1 < T) ? ((k1 < len) && (k1 > p)) : ((k1 - T) < p);
      float2 sv;
      sv.x = v0 ? acc0 : -__builtin_inff();
      sv.y = v1 ? acc1 : -__builtin_inff();
      *(float2*)&sc[prow][k0] = sv;
    }
  }
  __syncthreads();

  // ---- softmax (wave-local rows) ----
  float inv[4];
#pragma unroll
  for (int pp = 0; pp < 4; ++pp) {
    const int prow = wv * 4 + pp;
    float m = -__builtin_inff();
    for (int k = lane; k < KPAD; k += 64) m = fmaxf(m, sc[prow][k]);
#pragma unroll
    for (int off = 32; off; off >>= 1) m = fmaxf(m, __shfl_xor(m, off, 64));
    float ssum = 0.f;
    for (int k = lane; k < KPAD; k += 64) {
      const float e = __builtin_amdgcn_exp2f((sc[prow][k] - m) * 1.44269504f);
      sc[prow][k] = e;
      ssum += e;
    }
#pragma unroll
    for (int off = 32; off; off >>= 1) ssum += __shfl_xor(ssum, off, 64);
    inv[pp] = __builtin_amdgcn_rcpf(ssum);
  }

  // ---- context, vc-chunked ----
  float ca[4] = {0.f, 0.f, 0.f, 0.f}, cb[4] = {0.f, 0.f, 0.f, 0.f};
  for (int vc = 0; vc < 5; ++vc) {
    __syncthreads();
    for (int it = tid; it < 2048; it += 512) {
      const int kk = it >> 4, hs = it & 15;
      int krow = vc * 128 + kk;
      if (krow > KEXT - 1) krow = KEXT - 1;  // pad row; weight sc[.][639]==0
      *(half8*)&stg[kk][hs * 8] =
          *(const half8*)(Vext + ((size_t)b * KEXT + krow) * HDIM + hs * 8);
    }
    __syncthreads();
#pragma unroll
    for (int pp = 0; pp < 4; ++pp) {
      const int prow = wv * 4 + pp;
      float a0 = ca[pp], a1 = cb[pp];
#pragma unroll 4
      for (int kk = 0; kk < 128; ++kk) {
        const float wgt = sc[prow][vc * 128 + kk];
        const half2t v = *(const half2t*)&stg[kk][lane * 2];
        a0 = fmaf(wgt, (float)v[0], a0);
        a1 = fmaf(wgt, (float)v[1], a1);
      }
      ca[pp] = a0; cb[pp] = a1;
    }
  }
#pragma unroll
  for (int pp = 0; pp < 4; ++pp) {
    const int prow = wv * 4 + pp;
    ctxs[prow][lane * 2]     = ca[pp] * inv[pp];
    ctxs[prow][lane * 2 + 1] = cb[pp] * inv[pp];
  }
  __syncthreads();

  // ---- head: relu(ctx@fc1^T+b1)@fc2^T+b2, fc2 via shuffle reduce ----
#pragma unroll
  for (int pp = 0; pp < 4; ++pp) {
    const int prow = wv * 4 + pp;
    float r = 0.f;
    if (lane < 32) {
      float a = fb;
      for (int h = 0; h < HDIM; ++h)
        a = fmaf(ctxs[prow][h], (float)f1[lane][h], a);
      r = fmaxf(a, 0.f);
    }
    float s0 = r * w2a, s1 = r * w2b;
#pragma unroll
    for (int off = 16; off; off >>= 1) {
      s0 += __shfl_xor(s0, off, 64);
      s1 += __shfl_xor(s1, off, 64);
    }
    if (lane == 0) {
      float* o = out + ((size_t)b * LOUT + p0 + prow) * 2;
      o[0] = s0 + f2b0;
      o[1] = s1 + f2b1;
    }
  }
}

// ---------------------------------------------------------------------------
extern "C" void kernel_launch(void* const* d_in, const int* in_sizes, int n_in,
                              void* d_out, int out_size, void* d_ws, size_t ws_size,
                              hipStream_t stream)
{
  const float* x     = (const float*)d_in[0];
  const float* y     = (const float*)d_in[1];
  const int* lengths = (const int*)d_in[3];
  const float* Wih0  = (const float*)d_in[4];
  const float* Whh0  = (const float*)d_in[5];
  const float* bih0  = (const float*)d_in[6];
  const float* bhh0  = (const float*)d_in[7];
  const float* Wih1  = (const float*)d_in[8];
  const float* Whh1  = (const float*)d_in[9];
  const float* bih1  = (const float*)d_in[10];
  const float* bhh1  = (const float*)d_in[11];
  const float* Wa    = (const float*)d_in[12];
  const float* bWa   = (const float*)d_in[13];
  const float* Ua    = (const float*)d_in[14];
  const float* bUa   = (const float*)d_in[15];
  const float* Va    = (const float*)d_in[16];
  const float* fc1w  = (const float*)d_in[18];
  const float* fc1b  = (const float*)d_in[19];
  const float* fc2w  = (const float*)d_in[20];
  const float* fc2b  = (const float*)d_in[21];

  char* wsp = (char*)d_ws;
  _Float16* Vext = (_Float16*)(wsp);              // 256*639*128*2  = 41,877,504
  _Float16* Hfin = (_Float16*)(wsp + 41877504);   // 256*128*2      =     65,536
  _Float16* tA   = (_Float16*)(wsp + 41943040);   // 256*128*640*2  = 41,943,040
  _Float16* tq   = (_Float16*)(wsp + 83886080);   // 256*128*128*2  =  8,388,608
  (void)in_sizes; (void)n_in; (void)out_size; (void)ws_size;

  lstm_kernel<<<16, 512, 0, stream>>>(x, y, lengths, Wih0, Whh0, bih0, bhh0,
                                      Wih1, Whh1, bih1, bhh1, Vext, Hfin);
  proj_kernel<<<256, 256, 0, stream>>>(Vext, Hfin, Wa, bWa, Ua, bUa, tA, tq);
  attn_kernel<<<dim3(256, 4), 512, 0, stream>>>(Vext, tA, tq, Va, lengths,
                                                fc1w, fc1b, fc2w, fc2b,
                                                (float*)d_out);
}

// Round 6
// 3554.550 us; speedup vs baseline: 1.4273x; 1.2369x over previous
//
#include <hip/hip_runtime.h>

#define T 512
#define HDIM 128
#define LOUT 128
#define KEXT 639
#define KPAD 640

typedef _Float16 half8 __attribute__((ext_vector_type(8)));
typedef _Float16 half4 __attribute__((ext_vector_type(4)));
typedef _Float16 half2t __attribute__((ext_vector_type(2)));
typedef float f32x4 __attribute__((ext_vector_type(4)));

__device__ __forceinline__ int clampT(int v) { return v < 0 ? 0 : (v > T ? T : v); }

__device__ __forceinline__ half8 load8f(const float* p) {
  float4 q0 = *(const float4*)p;
  float4 q1 = *(const float4*)(p + 4);
  half8 v;
  v[0] = (_Float16)q0.x; v[1] = (_Float16)q0.y; v[2] = (_Float16)q0.z; v[3] = (_Float16)q0.w;
  v[4] = (_Float16)q1.x; v[5] = (_Float16)q1.y; v[6] = (_Float16)q1.z; v[7] = (_Float16)q1.w;
  return v;
}

// merged-denominator LSTM cell: 5 exp2 + 3 rcp per cell
__device__ __forceinline__ void cell_up(float gi, float gf, float gg, float go,
                                        float& cr, _Float16& hh, bool v) {
  const float A = 1.44269504f, B2 = 2.88539008f;
  const float Fi = __builtin_amdgcn_exp2f(-gi * A);
  const float Ff = __builtin_amdgcn_exp2f(-gf * A);
  const float Fo = __builtin_amdgcn_exp2f(-go * A);
  const float Eg = __builtin_amdgcn_exp2f(gg * B2);
  const float it = (Eg - 1.f) * __builtin_amdgcn_rcpf((1.f + Fi) * (1.f + Eg));
  const float cn = cr * __builtin_amdgcn_rcpf(1.f + Ff) + it;
  const float ec = __builtin_amdgcn_exp2f(-B2 * __builtin_fabsf(cn));
  const float h  = __builtin_copysignf(
      (1.f - ec) * __builtin_amdgcn_rcpf((1.f + Fo) * (1.f + ec)), cn);
  if (v) { cr = cn; hh = (_Float16)h; }
}

// fast tanh for proj kernel
__device__ __forceinline__ float fast_tanh(float x) {
  float ax = __builtin_fabsf(x);
  float e = __builtin_amdgcn_exp2f(ax * -2.88539008f);
  float t = (1.f - e) * __builtin_amdgcn_rcpf(1.f + e);
  return __builtin_copysignf(t, x);
}

// ---------------------------------------------------------------------------
// Kernel A: persistent 2-layer LSTM. 16 WGs x 512 threads, 16 batch rows/WG.
// Whh0+Whh1 fragments resident in VGPRs (128 regs; waves_per_eu(2,2) unlocks
// the 256-reg budget); Wih1 staged in LDS (128 KiB). h1/h2 stored in LDS in
// MFMA-fragment order (conflict-free ds_read_b128). One barrier per step.
// ---------------------------------------------------------------------------
__global__ __launch_bounds__(512) __attribute__((amdgpu_waves_per_eu(2, 2)))
void lstm_kernel(const float* __restrict__ x, const float* __restrict__ y,
                 const int* __restrict__ lengths,
                 const float* __restrict__ Wih0, const float* __restrict__ Whh0,
                 const float* __restrict__ bih0, const float* __restrict__ bhh0,
                 const float* __restrict__ Wih1, const float* __restrict__ Whh1,
                 const float* __restrict__ bih1, const float* __restrict__ bhh1,
                 _Float16* __restrict__ Vext, _Float16* __restrict__ Hfin)
{
  const int tid  = threadIdx.x;
  const int w    = tid >> 6;
  const int lane = tid & 63;
  const int fr   = lane & 15;
  const int fg   = lane >> 4;
  const int b0   = blockIdx.x * 16;
  const int u    = w * 16 + fr;                    // owned hidden unit
  const int ubase = (u >> 3) * 128 + (u & 7);      // frag-order base for writes

  __shared__ _Float16 w1lds[8][4][4][4][16][8];    // 128 KiB: Wih1 fragments
  __shared__ _Float16 h1buf[2][2048];              // frag-order h1 (dbuf)
  __shared__ _Float16 h2buf[2][2048];              // frag-order h2 (dbuf)
  __shared__ float    xst[2][16][4];
  __shared__ int      lens_s[16];

  // resident Whh0/Whh1 fragments + per-unit constants
  half8 bh0r[4][4], bh1r[4][4];
  float w0r[4][3], b0r[4], b1r[4];
#pragma unroll
  for (int g = 0; g < 4; ++g) {
    const int n = g * 128 + u;
    b0r[g] = bih0[n] + bhh0[n];
    b1r[g] = bih1[n] + bhh1[n];
    w0r[g][0] = Wih0[n * 3 + 0];
    w0r[g][1] = Wih0[n * 3 + 1];
    w0r[g][2] = Wih0[n * 3 + 2];
#pragma unroll
    for (int kf = 0; kf < 4; ++kf) {
      bh0r[g][kf] = load8f(Whh0 + n * HDIM + kf * 32 + fg * 8);
      bh1r[g][kf] = load8f(Whh1 + n * HDIM + kf * 32 + fg * 8);
    }
  }

  if (tid < 16) lens_s[tid] = clampT(lengths[b0 + tid]);
  for (int it = tid; it < 2048; it += 512) {
    h1buf[0][it] = (_Float16)0.f; h1buf[1][it] = (_Float16)0.f;
    h2buf[0][it] = (_Float16)0.f; h2buf[1][it] = (_Float16)0.f;
  }
  // stage Wih1 fragments
  for (int c = tid; c < 8192; c += 512) {
    const int n = c >> 4, k8 = c & 15;
    *(half8*)&w1lds[(n >> 4) & 7][n >> 7][k8 >> 2][k8 & 3][n & 15][0] =
        load8f(Wih1 + n * HDIM + k8 * 8);
  }
  __syncthreads();

  int mylen[4];
#pragma unroll
  for (int j = 0; j < 4; ++j) mylen[j] = lens_s[fg * 4 + j];
  int maxlen = 0, minlen = T;
  for (int i = 0; i < 16; ++i) {
    maxlen = max(maxlen, lens_s[i]);
    minlen = min(minlen, lens_s[i]);
  }
  const int S = maxlen + LOUT - 1;

  // zero-fill encoder rows past each length
  {
    const int zbi = tid >> 5, zu = (tid & 31) * 4;
    const int zlen = lens_s[zbi];
    const half4 z = {(_Float16)0.f, (_Float16)0.f, (_Float16)0.f, (_Float16)0.f};
    for (int t = minlen; t < T; ++t)
      if (t >= zlen)
        *(half4*)(Vext + ((size_t)(b0 + zbi) * KEXT + t) * HDIM + zu) = z;
  }
  // stage inputs for steps 0 and 1
  if (tid < 48) {
    const int sbi = tid / 3, sj = tid - sbi * 3;
    xst[0][sbi][sj] = (0 < maxlen) ? x[((size_t)(b0 + sbi) * T) * 3 + sj]
                                   : y[((size_t)(b0 + sbi) * LOUT) * 3 + sj];
    xst[1][sbi][sj] = (1 < maxlen) ? x[((size_t)(b0 + sbi) * T + 1) * 3 + sj]
                                   : y[((size_t)(b0 + sbi) * LOUT + (1 - maxlen)) * 3 + sj];
  }
  __syncthreads();

  float c1r[4] = {0.f, 0.f, 0.f, 0.f}, c2r[4] = {0.f, 0.f, 0.f, 0.f};
  _Float16 h1h[4] = {(_Float16)0.f, (_Float16)0.f, (_Float16)0.f, (_Float16)0.f};
  _Float16 h2h[4] = {(_Float16)0.f, (_Float16)0.f, (_Float16)0.f, (_Float16)0.f};

  // cell0(0): h1(-1)=0 -> gates = b0 + Wih0*x(0)
#pragma unroll
  for (int j = 0; j < 4; ++j) {
    const int bidx = fg * 4 + j;
    const float x0 = xst[0][bidx][0], x1 = xst[0][bidx][1], x2 = xst[0][bidx][2];
    float gv[4];
#pragma unroll
    for (int g = 0; g < 4; ++g)
      gv[g] = b0r[g] + x0 * w0r[g][0] + x1 * w0r[g][1] + x2 * w0r[g][2];
    cell_up(gv[0], gv[1], gv[2], gv[3], c1r[j], h1h[j], (0 >= maxlen) || (0 < mylen[j]));
    h1buf[0][ubase + bidx * 8] = h1h[j];
  }
  __syncthreads();

  for (int s = 0; s < S; ++s) {
    const int p = s & 1;
    // ---- flush h2(s-1) from LDS: contiguous 8B/thread, hides under MFMA ----
    if (s > 0) {
      const int prow = s - 1;
      const half4 hv = *(const half4*)&h2buf[p ^ 1][tid * 4];
      const int frow = (tid >> 1) & 15;
      const int k0 = (tid >> 5) * 8 + (tid & 1) * 4;
      const int orow = (prow < maxlen) ? prow : (T + prow - maxlen);
      if ((prow >= maxlen) || (prow < lens_s[frow]))
        *(half4*)(Vext + ((size_t)(b0 + frow) * KEXT + orow) * HDIM + k0) = hv;
      if (prow == maxlen - 1)
        *(half4*)(Hfin + (size_t)(b0 + frow) * HDIM + k0) = hv;
    }
    // ---- prefetch input(s+2) ----
    float xr = 0.f; int sbi = 0, sj = 0;
    const bool havex = (tid < 48) && (s + 2 < S);
    if (havex) {
      sbi = tid / 3; sj = tid - sbi * 3;
      const int k = s + 2;
      xr = (k < maxlen) ? x[((size_t)(b0 + sbi) * T + k) * 3 + sj]
                        : y[((size_t)(b0 + sbi) * LOUT + (k - maxlen)) * 3 + sj];
    }
    // ---- A-fragments (conflict-free b128) ----
    half8 h1f[4], h2f[4];
#pragma unroll
    for (int kf = 0; kf < 4; ++kf) {
      h1f[kf] = *(const half8*)&h1buf[p][(kf * 4 + fg) * 128 + fr * 8];
      h2f[kf] = *(const half8*)&h2buf[p ^ 1][(kf * 4 + fg) * 128 + fr * 8];
    }
    // ---- G1(s) = h1(s)@Wih1^T + h2(s-1)@Whh1^T + b1 ----
    f32x4 acc[4];
#pragma unroll
    for (int g = 0; g < 4; ++g) {
      f32x4 a = {b1r[g], b1r[g], b1r[g], b1r[g]};
#pragma unroll
      for (int kf = 0; kf < 4; ++kf)
        a = __builtin_amdgcn_mfma_f32_16x16x32_f16(
                h1f[kf], *(const half8*)&w1lds[w][g][kf][fg][fr][0], a, 0, 0, 0);
#pragma unroll
      for (int kf = 0; kf < 4; ++kf)
        a = __builtin_amdgcn_mfma_f32_16x16x32_f16(h2f[kf], bh1r[g][kf], a, 0, 0, 0);
      acc[g] = a;
    }
    // ---- cell1(s): gates live in acc ----
#pragma unroll
    for (int j = 0; j < 4; ++j) {
      cell_up(acc[0][j], acc[1][j], acc[2][j], acc[3][j], c2r[j], h2h[j],
              (s >= maxlen) || (s < mylen[j]));
      h2buf[p][ubase + (fg * 4 + j) * 8] = h2h[j];
    }
    if (s + 1 < S) {
      // ---- G0(s+1) = h1(s)@Whh0^T (h1f reused, weights in regs) ----
#pragma unroll
      for (int g = 0; g < 4; ++g) {
        f32x4 a = {0.f, 0.f, 0.f, 0.f};
#pragma unroll
        for (int kf = 0; kf < 4; ++kf)
          a = __builtin_amdgcn_mfma_f32_16x16x32_f16(h1f[kf], bh0r[g][kf], a, 0, 0, 0);
        acc[g] = a;
      }
      if (havex) xst[p][sbi][sj] = xr;
      const int p1 = p ^ 1;
      // ---- cell0(s+1) ----
#pragma unroll
      for (int j = 0; j < 4; ++j) {
        const int bidx = fg * 4 + j;
        const float x0 = xst[p1][bidx][0], x1 = xst[p1][bidx][1], x2 = xst[p1][bidx][2];
        const float gi = acc[0][j] + b0r[0] + x0 * w0r[0][0] + x1 * w0r[0][1] + x2 * w0r[0][2];
        const float gf = acc[1][j] + b0r[1] + x0 * w0r[1][0] + x1 * w0r[1][1] + x2 * w0r[1][2];
        const float gg = acc[2][j] + b0r[2] + x0 * w0r[2][0] + x1 * w0r[2][1] + x2 * w0r[2][2];
        const float go = acc[3][j] + b0r[3] + x0 * w0r[3][0] + x1 * w0r[3][1] + x2 * w0r[3][2];
        cell_up(gi, gf, gg, go, c1r[j], h1h[j], (s + 1 >= maxlen) || (s + 1 < mylen[j]));
        h1buf[p1][ubase + bidx * 8] = h1h[j];
      }
    }
    __syncthreads();
  }
  // final flush: step S-1 -> decoder row 638
  {
    const half4 hv = *(const half4*)&h2buf[(S - 1) & 1][tid * 4];
    const int frow = (tid >> 1) & 15;
    const int k0 = (tid >> 5) * 8 + (tid & 1) * 4;
    const int orow = T + (S - 1) - maxlen;
    *(half4*)(Vext + ((size_t)(b0 + frow) * KEXT + orow) * HDIM + k0) = hv;
  }
}

// ---------------------------------------------------------------------------
// Kernel B: tA[b][h][k] = tanh(Vext[b][k] @ Wa^T + bWa)  (fp16, k-major)
//           tq[b][p][h] = tanh(Q_p @ Ua^T + bUa)         (fp16)
// ---------------------------------------------------------------------------
__global__ __launch_bounds__(256, 1)
void proj_kernel(const _Float16* __restrict__ Vext, const _Float16* __restrict__ Hfin,
                 const float* __restrict__ Wa, const float* __restrict__ bWa,
                 const float* __restrict__ Ua, const float* __restrict__ bUa,
                 _Float16* __restrict__ tA, _Float16* __restrict__ tq)
{
  const int b = blockIdx.x;
  const int tid = threadIdx.x;
  const int wave = tid >> 6, lane = tid & 63;
  const int fr = lane & 15, fg = lane >> 4;
  __shared__ _Float16 tile[4][128][24];

  half8 bf[8][4];
  float bias_r[8];
#pragma unroll
  for (int nt = 0; nt < 8; ++nt) {
    const int ho = nt * 16 + fr;
    bias_r[nt] = bWa[ho];
#pragma unroll
    for (int kf = 0; kf < 4; ++kf)
      bf[nt][kf] = load8f(Wa + ho * HDIM + kf * 32 + fg * 8);
  }

  for (int r = 0; r < 10; ++r) {
    const int mt = r * 4 + wave;
    int row = mt * 16 + fr;
    if (row > KEXT - 1) row = KEXT - 1;
    const _Float16* src = Vext + ((size_t)b * KEXT + row) * HDIM;
    half8 af[4];
#pragma unroll
    for (int kf = 0; kf < 4; ++kf) af[kf] = *(const half8*)(src + kf * 32 + fg * 8);
#pragma unroll
    for (int nt = 0; nt < 8; ++nt) {
      f32x4 a = {0.f, 0.f, 0.f, 0.f};
#pragma unroll
      for (int kf = 0; kf < 4; ++kf)
        a = __builtin_amdgcn_mfma_f32_16x16x32_f16(af[kf], bf[nt][kf], a, 0, 0, 0);
#pragma unroll
      for (int j = 0; j < 4; ++j)
        tile[wave][nt * 16 + fr][fg * 4 + j] = (_Float16)fast_tanh(a[j] + bias_r[nt]);
    }
    __syncthreads();
    for (int it = tid; it < 4 * 128; it += 256) {
      const int w2 = it >> 7, ho = it & 127;
      const half8 v0 = *(const half8*)&tile[w2][ho][0];
      const half8 v1 = *(const half8*)&tile[w2][ho][8];
      _Float16* dst = tA + ((size_t)b * HDIM + ho) * KPAD + (r * 4 + w2) * 16;
      *(half8*)dst = v0;
      *(half8*)(dst + 8) = v1;
    }
    __syncthreads();
  }

#pragma unroll
  for (int nt = 0; nt < 8; ++nt) {
    const int ho = nt * 16 + fr;
    bias_r[nt] = bUa[ho];
#pragma unroll
    for (int kf = 0; kf < 4; ++kf)
      bf[nt][kf] = load8f(Ua + ho * HDIM + kf * 32 + fg * 8);
  }
  for (int r = 0; r < 2; ++r) {
    const int mt = r * 4 + wave;
    const int prow = mt * 16 + fr;
    const _Float16* src = (prow == 0)
        ? (Hfin + (size_t)b * HDIM)
        : (Vext + ((size_t)b * KEXT + 511 + prow) * HDIM);
    half8 af[4];
#pragma unroll
    for (int kf = 0; kf < 4; ++kf) af[kf] = *(const half8*)(src + kf * 32 + fg * 8);
#pragma unroll
    for (int nt = 0; nt < 8; ++nt) {
      f32x4 a = {0.f, 0.f, 0.f, 0.f};
#pragma unroll
      for (int kf = 0; kf < 4; ++kf)
        a = __builtin_amdgcn_mfma_f32_16x16x32_f16(af[kf], bf[nt][kf], a, 0, 0, 0);
#pragma unroll
      for (int j = 0; j < 4; ++j) {
        const int pq = mt * 16 + fg * 4 + j;
        tq[((size_t)b * LOUT + pq) * HDIM + nt * 16 + fr] = (_Float16)fast_tanh(a[j] + bias_r[nt]);
      }
    }
  }
}

// ---------------------------------------------------------------------------
// Kernel C: attention. grid (B, 8 p-blocks of 16), 512 thr, 2 queries/wave.
// LDS 64.5 KiB -> 2 WGs/CU. fp16 scores; masked chunks skipped exactly.
// ---------------------------------------------------------------------------
__global__ __launch_bounds__(512)
void attn_kernel(const _Float16* __restrict__ Vext,
                 const _Float16* __restrict__ tA,
                 const _Float16* __restrict__ tq,
                 const float* __restrict__ Va,
                 const int* __restrict__ lengths,
                 const float* __restrict__ fc1w, const float* __restrict__ fc1b,
                 const float* __restrict__ fc2w, const float* __restrict__ fc2b,
                 float* __restrict__ out)
{
  const int b = blockIdx.x;
  const int p0 = blockIdx.y * 16;
  const int tid = threadIdx.x, wv = tid >> 6, lane = tid & 63;

  __shared__ __align__(16) char stg_raw[128 * 136 * 2];  // 34 KiB staging / f1+ctx alias
  __shared__ __align__(16) char sc_raw[16 * 648 * 2];    // 20.7 KiB fp16 scores / ctx alias
  __shared__ float qs[16][132];
  __shared__ float vas[HDIM];
  auto stg = (_Float16(*)[136])stg_raw;
  auto sc  = (_Float16(*)[648])sc_raw;

  for (int it = tid; it < 16 * HDIM; it += 512)
    qs[it >> 7][it & 127] = (float)tq[((size_t)b * LOUT + p0 + (it >> 7)) * HDIM + (it & 127)];
  if (tid < HDIM) vas[tid] = Va[tid];
  const int len = clampT(lengths[b]);
  const float fb   = (lane < 32) ? fc1b[lane] : 0.f;
  const float w2a  = (lane < 32) ? fc2w[lane] : 0.f;
  const float w2b  = (lane < 32) ? fc2w[32 + lane] : 0.f;
  const float f2b0 = fc2b[0], f2b1 = fc2b[1];
  const _Float16 NEGINF = (_Float16)(-__builtin_inff());
  __syncthreads();

  // ---- scores (5 chunks of 128 keys) ----
  for (int kc = 0; kc < 5; ++kc) {
    const int ck0 = kc * 128;
    const bool alive = (ck0 < T) ? ((ck0 == 0) || (ck0 < len))
                                 : ((ck0 - T) < p0 + 15);
    if (alive) {
      __syncthreads();
      for (int it = tid; it < 2048; it += 512) {
        const int hh = it >> 4, ks = it & 15;
        *(half8*)&stg[hh][ks * 8] =
            *(const half8*)(tA + ((size_t)b * HDIM + hh) * KPAD + ck0 + ks * 8);
      }
      __syncthreads();
    }
#pragma unroll
    for (int pp = 0; pp < 2; ++pp) {
      const int prow = wv * 2 + pp;
      const int p = p0 + prow;
      const int k0 = ck0 + lane * 2, k1 = k0 + 1;
      bool anyv;
      if (ck0 < T) {
        const int kmax = min(ck0 + 127, len - 1);
        anyv = (ck0 == 0) || ((ck0 < len) && (kmax > p));
      } else {
        anyv = (ck0 - T) < p;
      }
      if (!anyv) {
        half2t z; z[0] = NEGINF; z[1] = NEGINF;
        *(half2t*)&sc[prow][k0] = z;
        continue;
      }
      float acc0 = 0.f, acc1 = 0.f;
#pragma unroll 4
      for (int h = 0; h < HDIM; ++h) {
        const half2t a = *(const half2t*)&stg[h][lane * 2];
        const float tqv = qs[prow][h];
        const float va = vas[h];
        const float a0 = (float)a[0], a1 = (float)a[1];
        const float t0 = (a0 + tqv) * __builtin_amdgcn_rcpf(fmaf(a0, tqv, 1.f));
        const float t1 = (a1 + tqv) * __builtin_amdgcn_rcpf(fmaf(a1, tqv, 1.f));
        acc0 = fmaf(va, t0, acc0);
        acc1 = fmaf(va, t1, acc1);
      }
      const bool v0 = (k0 < T) ? ((k0 < len) && (k0 == 0 || k0 > p)) : ((k0 - T) < p);
      const bool v1 = (k1 < T) ? ((k1 < len) && (k1 > p)) : ((k1 - T) < p);
      half2t sv;
      sv[0] = v0 ? (_Float16)acc0 : NEGINF;
      sv[1] = v1 ? (_Float16)acc1 : NEGINF;
      *(half2t*)&sc[prow][k0] = sv;
    }
  }

  // ---- softmax (wave-local rows, no barrier needed) ----
  float inv[2];
#pragma unroll
  for (int pp = 0; pp < 2; ++pp) {
    const int prow = wv * 2 + pp;
    float m = -__builtin_inff();
    for (int k = lane; k < KPAD; k += 64) m = fmaxf(m, (float)sc[prow][k]);
#pragma unroll
    for (int off = 32; off; off >>= 1) m = fmaxf(m, __shfl_xor(m, off, 64));
    float ssum = 0.f;
    for (int k = lane; k < KPAD; k += 64) {
      const float e = __builtin_amdgcn_exp2f(((float)sc[prow][k] - m) * 1.44269504f);
      sc[prow][k] = (_Float16)e;
      ssum += e;
    }
#pragma unroll
    for (int off = 32; off; off >>= 1) ssum += __shfl_xor(ssum, off, 64);
    inv[pp] = __builtin_amdgcn_rcpf(ssum);
  }

  // ---- context (5 chunks of 128 keys) ----
  float ca[2] = {0.f, 0.f}, cb[2] = {0.f, 0.f};
  for (int vc = 0; vc < 5; ++vc) {
    const int ck0 = vc * 128;
    const bool alive = (ck0 < T) ? ((ck0 == 0) || (ck0 < len))
                                 : ((ck0 - T) < p0 + 15);
    if (!alive) continue;
    __syncthreads();
    for (int it = tid; it < 2048; it += 512) {
      const int kk = it >> 4, hs = it & 15;
      const int krow = min(ck0 + kk, KEXT - 1);
      *(half8*)&stg[kk][hs * 8] =
          *(const half8*)(Vext + ((size_t)b * KEXT + krow) * HDIM + hs * 8);
    }
    __syncthreads();
#pragma unroll
    for (int pp = 0; pp < 2; ++pp) {
      const int prow = wv * 2 + pp;
      const int p = p0 + prow;
      bool anyv;
      if (ck0 < T) {
        const int kmax = min(ck0 + 127, len - 1);
        anyv = (ck0 == 0) || ((ck0 < len) && (kmax > p));
      } else {
        anyv = (ck0 - T) < p;
      }
      if (!anyv) continue;
      float a0 = ca[pp], a1 = cb[pp];
#pragma unroll 4
      for (int kk = 0; kk < 128; ++kk) {
        const float wgt = (float)sc[prow][ck0 + kk];
        const half2t v = *(const half2t*)&stg[kk][lane * 2];
        a0 = fmaf(wgt, (float)v[0], a0);
        a1 = fmaf(wgt, (float)v[1], a1);
      }
      ca[pp] = a0; cb[pp] = a1;
    }
  }
  __syncthreads();   // protect sc->ctx and stg->f1 aliasing

  auto ctxs = (float(*)[128])sc_raw;
  auto f1   = (_Float16(*)[132])stg_raw;
#pragma unroll
  for (int pp = 0; pp < 2; ++pp) {
    const int prow = wv * 2 + pp;
    float2 cv; cv.x = ca[pp] * inv[pp]; cv.y = cb[pp] * inv[pp];
    *(float2*)&ctxs[prow][lane * 2] = cv;
  }
  for (int it = tid; it < 32 * HDIM; it += 512)
    f1[it >> 7][it & 127] = (_Float16)fc1w[it];
  __syncthreads();

  // ---- head: relu(ctx@fc1^T+b1)@fc2^T+b2, fc2 via shuffle reduce ----
#pragma unroll
  for (int pp = 0; pp < 2; ++pp) {
    const int prow = wv * 2 + pp;
    float r = 0.f;
    if (lane < 32) {
      float a = fb;
      for (int h = 0; h < HDIM; ++h)
        a = fmaf(ctxs[prow][h], (float)f1[lane][h], a);
      r = fmaxf(a, 0.f);
    }
    float s0 = r * w2a, s1 = r * w2b;
#pragma unroll
    for (int off = 16; off; off >>= 1) {
      s0 += __shfl_xor(s0, off, 64);
      s1 += __shfl_xor(s1, off, 64);
    }
    if (lane == 0) {
      float* o = out + ((size_t)b * LOUT + p0 + prow) * 2;
      o[0] = s0 + f2b0;
      o[1] = s1 + f2b1;
    }
  }
}

// ---------------------------------------------------------------------------
extern "C" void kernel_launch(void* const* d_in, const int* in_sizes, int n_in,
                              void* d_out, int out_size, void* d_ws, size_t ws_size,
                              hipStream_t stream)
{
  const float* x     = (const float*)d_in[0];
  const float* y     = (const float*)d_in[1];
  const int* lengths = (const int*)d_in[3];
  const float* Wih0  = (const float*)d_in[4];
  const float* Whh0  = (const float*)d_in[5];
  const float* bih0  = (const float*)d_in[6];
  const float* bhh0  = (const float*)d_in[7];
  const float* Wih1  = (const float*)d_in[8];
  const float* Whh1  = (const float*)d_in[9];
  const float* bih1  = (const float*)d_in[10];
  const float* bhh1  = (const float*)d_in[11];
  const float* Wa    = (const float*)d_in[12];
  const float* bWa   = (const float*)d_in[13];
  const float* Ua    = (const float*)d_in[14];
  const float* bUa   = (const float*)d_in[15];
  const float* Va    = (const float*)d_in[16];
  const float* fc1w  = (const float*)d_in[18];
  const float* fc1b  = (const float*)d_in[19];
  const float* fc2w  = (const float*)d_in[20];
  const float* fc2b  = (const float*)d_in[21];

  char* wsp = (char*)d_ws;
  _Float16* Vext = (_Float16*)(wsp);              // 256*639*128*2  = 41,877,504
  _Float16* Hfin = (_Float16*)(wsp + 41877504);   // 256*128*2      =     65,536
  _Float16* tA   = (_Float16*)(wsp + 41943040);   // 256*128*640*2  = 41,943,040
  _Float16* tq   = (_Float16*)(wsp + 83886080);   // 256*128*128*2  =  8,388,608
  (void)in_sizes; (void)n_in; (void)out_size; (void)ws_size;

  lstm_kernel<<<16, 512, 0, stream>>>(x, y, lengths, Wih0, Whh0, bih0, bhh0,
                                      Wih1, Whh1, bih1, bhh1, Vext, Hfin);
  proj_kernel<<<256, 256, 0, stream>>>(Vext, Hfin, Wa, bWa, Ua, bUa, tA, tq);
  attn_kernel<<<dim3(256, 8), 512, 0, stream>>>(Vext, tA, tq, Va, lengths,
                                                fc1w, fc1b, fc2w, fc2b,
                                                (float*)d_out);
}

// Round 7
// 2807.938 us; speedup vs baseline: 1.8068x; 1.2659x over previous
//
#include <hip/hip_runtime.h>

#define T 512
#define HDIM 128
#define LOUT 128
#define KEXT 639
#define KPAD 640

typedef _Float16 half8 __attribute__((ext_vector_type(8)));
typedef _Float16 half4 __attribute__((ext_vector_type(4)));
typedef _Float16 half2t __attribute__((ext_vector_type(2)));
typedef float f32x4 __attribute__((ext_vector_type(4)));
typedef unsigned int u32x4 __attribute__((ext_vector_type(4)));

__device__ __forceinline__ int clampT(int v) { return v < 0 ? 0 : (v > T ? T : v); }

__device__ __forceinline__ half8 load8f(const float* p) {
  float4 q0 = *(const float4*)p;
  float4 q1 = *(const float4*)(p + 4);
  half8 v;
  v[0] = (_Float16)q0.x; v[1] = (_Float16)q0.y; v[2] = (_Float16)q0.z; v[3] = (_Float16)q0.w;
  v[4] = (_Float16)q1.x; v[5] = (_Float16)q1.y; v[6] = (_Float16)q1.z; v[7] = (_Float16)q1.w;
  return v;
}

// volatile 16B load: cannot be rematerialized -> value must stay resident
__device__ __forceinline__ half8 load8h_once(const _Float16* p) {
  u32x4 raw = *(volatile const u32x4*)p;
  return __builtin_bit_cast(half8, raw);
}

// merged-denominator LSTM cell: 5 exp2 + 3 rcp per cell
__device__ __forceinline__ void cell_up(float gi, float gf, float gg, float go,
                                        float& cr, _Float16& hh, bool v) {
  const float A = 1.44269504f, B2 = 2.88539008f;
  const float Fi = __builtin_amdgcn_exp2f(-gi * A);
  const float Ff = __builtin_amdgcn_exp2f(-gf * A);
  const float Fo = __builtin_amdgcn_exp2f(-go * A);
  const float Eg = __builtin_amdgcn_exp2f(gg * B2);
  const float it = (Eg - 1.f) * __builtin_amdgcn_rcpf((1.f + Fi) * (1.f + Eg));
  const float cn = cr * __builtin_amdgcn_rcpf(1.f + Ff) + it;
  const float ec = __builtin_amdgcn_exp2f(-B2 * __builtin_fabsf(cn));
  const float h  = __builtin_copysignf(
      (1.f - ec) * __builtin_amdgcn_rcpf((1.f + Fo) * (1.f + ec)), cn);
  if (v) { cr = cn; hh = (_Float16)h; }
}

__device__ __forceinline__ float fast_tanh(float x) {
  float ax = __builtin_fabsf(x);
  float e = __builtin_amdgcn_exp2f(ax * -2.88539008f);
  float t = (1.f - e) * __builtin_amdgcn_rcpf(1.f + e);
  return __builtin_copysignf(t, x);
}

// ---------------------------------------------------------------------------
// Kernel P: one-time fp32 -> fp16 conversion of Whh0 / Whh1 (row-major kept)
// ---------------------------------------------------------------------------
__global__ __launch_bounds__(256)
void prep_kernel(const float* __restrict__ Whh0, const float* __restrict__ Whh1,
                 _Float16* __restrict__ W0, _Float16* __restrict__ W1)
{
  const int i = (blockIdx.x * 256 + threadIdx.x) * 4;   // 64 blocks -> 65536 elems
  float4 a = *(const float4*)(Whh0 + i);
  float4 b = *(const float4*)(Whh1 + i);
  half4 ha = {(_Float16)a.x, (_Float16)a.y, (_Float16)a.z, (_Float16)a.w};
  half4 hb = {(_Float16)b.x, (_Float16)b.y, (_Float16)b.z, (_Float16)b.w};
  *(half4*)(W0 + i) = ha;
  *(half4*)(W1 + i) = hb;
}

// ---------------------------------------------------------------------------
// Kernel A: persistent 2-layer LSTM. 16 WGs x 512 threads, 16 batch rows/WG.
// Whh0+Whh1 fragments loaded ONCE via volatile 16B fp16 loads (remat-proof,
// stay resident in 128 regs); Wih1 staged in LDS (128 KiB). h1/h2 in LDS in
// MFMA-fragment order (conflict-free ds_read_b128). One barrier per step.
// ---------------------------------------------------------------------------
__global__ __launch_bounds__(512) __attribute__((amdgpu_waves_per_eu(2, 2)))
void lstm_kernel(const float* __restrict__ x, const float* __restrict__ y,
                 const int* __restrict__ lengths,
                 const float* __restrict__ Wih0,
                 const _Float16* __restrict__ W16_0,   // fp16 Whh0
                 const float* __restrict__ bih0, const float* __restrict__ bhh0,
                 const float* __restrict__ Wih1,
                 const _Float16* __restrict__ W16_1,   // fp16 Whh1
                 const float* __restrict__ bih1, const float* __restrict__ bhh1,
                 _Float16* __restrict__ Vext, _Float16* __restrict__ Hfin)
{
  const int tid  = threadIdx.x;
  const int w    = tid >> 6;
  const int lane = tid & 63;
  const int fr   = lane & 15;
  const int fg   = lane >> 4;
  const int b0   = blockIdx.x * 16;
  const int u    = w * 16 + fr;                    // owned hidden unit
  const int ubase = (u >> 3) * 128 + (u & 7);      // frag-order base for writes

  __shared__ _Float16 w1lds[8][4][4][4][16][8];    // 128 KiB: Wih1 fragments
  __shared__ _Float16 h1buf[2][2048];              // frag-order h1 (dbuf)
  __shared__ _Float16 h2buf[2][2048];              // frag-order h2 (dbuf)
  __shared__ float    xst[2][16][4];
  __shared__ int      lens_s[16];

  // resident Whh0/Whh1 fragments (volatile loads: executed exactly once)
  half8 bh0r[4][4], bh1r[4][4];
  float w0r[4][3], b0r[4], b1r[4];
#pragma unroll
  for (int g = 0; g < 4; ++g) {
    const int n = g * 128 + u;
    b0r[g] = bih0[n] + bhh0[n];
    b1r[g] = bih1[n] + bhh1[n];
    w0r[g][0] = Wih0[n * 3 + 0];
    w0r[g][1] = Wih0[n * 3 + 1];
    w0r[g][2] = Wih0[n * 3 + 2];
#pragma unroll
    for (int kf = 0; kf < 4; ++kf) {
      bh0r[g][kf] = load8h_once(W16_0 + n * HDIM + kf * 32 + fg * 8);
      bh1r[g][kf] = load8h_once(W16_1 + n * HDIM + kf * 32 + fg * 8);
    }
  }

  if (tid < 16) lens_s[tid] = clampT(lengths[b0 + tid]);
  for (int it = tid; it < 2048; it += 512) {
    h1buf[0][it] = (_Float16)0.f; h1buf[1][it] = (_Float16)0.f;
    h2buf[0][it] = (_Float16)0.f; h2buf[1][it] = (_Float16)0.f;
  }
  // stage Wih1 fragments
  for (int c = tid; c < 8192; c += 512) {
    const int n = c >> 4, k8 = c & 15;
    *(half8*)&w1lds[(n >> 4) & 7][n >> 7][k8 >> 2][k8 & 3][n & 15][0] =
        load8f(Wih1 + n * HDIM + k8 * 8);
  }
  __syncthreads();

  int mylen[4];
#pragma unroll
  for (int j = 0; j < 4; ++j) mylen[j] = lens_s[fg * 4 + j];
  int maxlen = 0, minlen = T;
  for (int i = 0; i < 16; ++i) {
    maxlen = max(maxlen, lens_s[i]);
    minlen = min(minlen, lens_s[i]);
  }
  const int S = maxlen + LOUT - 1;

  // zero-fill encoder rows past each length
  {
    const int zbi = tid >> 5, zu = (tid & 31) * 4;
    const int zlen = lens_s[zbi];
    const half4 z = {(_Float16)0.f, (_Float16)0.f, (_Float16)0.f, (_Float16)0.f};
    for (int t = minlen; t < T; ++t)
      if (t >= zlen)
        *(half4*)(Vext + ((size_t)(b0 + zbi) * KEXT + t) * HDIM + zu) = z;
  }
  // stage inputs for steps 0 and 1
  if (tid < 48) {
    const int sbi = tid / 3, sj = tid - sbi * 3;
    xst[0][sbi][sj] = (0 < maxlen) ? x[((size_t)(b0 + sbi) * T) * 3 + sj]
                                   : y[((size_t)(b0 + sbi) * LOUT) * 3 + sj];
    xst[1][sbi][sj] = (1 < maxlen) ? x[((size_t)(b0 + sbi) * T + 1) * 3 + sj]
                                   : y[((size_t)(b0 + sbi) * LOUT + (1 - maxlen)) * 3 + sj];
  }
  __syncthreads();

  float c1r[4] = {0.f, 0.f, 0.f, 0.f}, c2r[4] = {0.f, 0.f, 0.f, 0.f};
  _Float16 h1h[4] = {(_Float16)0.f, (_Float16)0.f, (_Float16)0.f, (_Float16)0.f};
  _Float16 h2h[4] = {(_Float16)0.f, (_Float16)0.f, (_Float16)0.f, (_Float16)0.f};

  // cell0(0): h1(-1)=0 -> gates = b0 + Wih0*x(0)
#pragma unroll
  for (int j = 0; j < 4; ++j) {
    const int bidx = fg * 4 + j;
    const float x0 = xst[0][bidx][0], x1 = xst[0][bidx][1], x2 = xst[0][bidx][2];
    float gv[4];
#pragma unroll
    for (int g = 0; g < 4; ++g)
      gv[g] = b0r[g] + x0 * w0r[g][0] + x1 * w0r[g][1] + x2 * w0r[g][2];
    cell_up(gv[0], gv[1], gv[2], gv[3], c1r[j], h1h[j], (0 >= maxlen) || (0 < mylen[j]));
    h1buf[0][ubase + bidx * 8] = h1h[j];
  }
  __syncthreads();

  for (int s = 0; s < S; ++s) {
    const int p = s & 1;
    // ---- flush h2(s-1) from LDS: contiguous 8B/thread, hides under MFMA ----
    if (s > 0) {
      const int prow = s - 1;
      const half4 hv = *(const half4*)&h2buf[p ^ 1][tid * 4];
      const int frow = (tid >> 1) & 15;
      const int k0 = (tid >> 5) * 8 + (tid & 1) * 4;
      const int orow = (prow < maxlen) ? prow : (T + prow - maxlen);
      if ((prow >= maxlen) || (prow < lens_s[frow]))
        *(half4*)(Vext + ((size_t)(b0 + frow) * KEXT + orow) * HDIM + k0) = hv;
      if (prow == maxlen - 1)
        *(half4*)(Hfin + (size_t)(b0 + frow) * HDIM + k0) = hv;
    }
    // ---- prefetch input(s+2) ----
    float xr = 0.f; int sbi = 0, sj = 0;
    const bool havex = (tid < 48) && (s + 2 < S);
    if (havex) {
      sbi = tid / 3; sj = tid - sbi * 3;
      const int k = s + 2;
      xr = (k < maxlen) ? x[((size_t)(b0 + sbi) * T + k) * 3 + sj]
                        : y[((size_t)(b0 + sbi) * LOUT + (k - maxlen)) * 3 + sj];
    }
    // ---- A-fragments (conflict-free b128) ----
    half8 h1f[4], h2f[4];
#pragma unroll
    for (int kf = 0; kf < 4; ++kf) {
      h1f[kf] = *(const half8*)&h1buf[p][(kf * 4 + fg) * 128 + fr * 8];
      h2f[kf] = *(const half8*)&h2buf[p ^ 1][(kf * 4 + fg) * 128 + fr * 8];
    }
    // ---- G1(s) = h1(s)@Wih1^T + h2(s-1)@Whh1^T + b1 ----
    f32x4 acc[4];
#pragma unroll
    for (int g = 0; g < 4; ++g) {
      f32x4 a = {b1r[g], b1r[g], b1r[g], b1r[g]};
#pragma unroll
      for (int kf = 0; kf < 4; ++kf)
        a = __builtin_amdgcn_mfma_f32_16x16x32_f16(
                h1f[kf], *(const half8*)&w1lds[w][g][kf][fg][fr][0], a, 0, 0, 0);
#pragma unroll
      for (int kf = 0; kf < 4; ++kf)
        a = __builtin_amdgcn_mfma_f32_16x16x32_f16(h2f[kf], bh1r[g][kf], a, 0, 0, 0);
      acc[g] = a;
    }
    // ---- cell1(s): gates live in acc ----
#pragma unroll
    for (int j = 0; j < 4; ++j) {
      cell_up(acc[0][j], acc[1][j], acc[2][j], acc[3][j], c2r[j], h2h[j],
              (s >= maxlen) || (s < mylen[j]));
      h2buf[p][ubase + (fg * 4 + j) * 8] = h2h[j];
    }
    if (s + 1 < S) {
      // ---- G0(s+1) = h1(s)@Whh0^T (h1f reused, weights resident) ----
#pragma unroll
      for (int g = 0; g < 4; ++g) {
        f32x4 a = {0.f, 0.f, 0.f, 0.f};
#pragma unroll
        for (int kf = 0; kf < 4; ++kf)
          a = __builtin_amdgcn_mfma_f32_16x16x32_f16(h1f[kf], bh0r[g][kf], a, 0, 0, 0);
        acc[g] = a;
      }
      if (havex) xst[p][sbi][sj] = xr;
      const int p1 = p ^ 1;
      // ---- cell0(s+1) ----
#pragma unroll
      for (int j = 0; j < 4; ++j) {
        const int bidx = fg * 4 + j;
        const float x0 = xst[p1][bidx][0], x1 = xst[p1][bidx][1], x2 = xst[p1][bidx][2];
        const float gi = acc[0][j] + b0r[0] + x0 * w0r[0][0] + x1 * w0r[0][1] + x2 * w0r[0][2];
        const float gf = acc[1][j] + b0r[1] + x0 * w0r[1][0] + x1 * w0r[1][1] + x2 * w0r[1][2];
        const float gg = acc[2][j] + b0r[2] + x0 * w0r[2][0] + x1 * w0r[2][1] + x2 * w0r[2][2];
        const float go = acc[3][j] + b0r[3] + x0 * w0r[3][0] + x1 * w0r[3][1] + x2 * w0r[3][2];
        cell_up(gi, gf, gg, go, c1r[j], h1h[j], (s + 1 >= maxlen) || (s + 1 < mylen[j]));
        h1buf[p1][ubase + bidx * 8] = h1h[j];
      }
    }
    __syncthreads();
  }
  // final flush: step S-1 -> decoder row 638
  {
    const half4 hv = *(const half4*)&h2buf[(S - 1) & 1][tid * 4];
    const int frow = (tid >> 1) & 15;
    const int k0 = (tid >> 5) * 8 + (tid & 1) * 4;
    const int orow = T + (S - 1) - maxlen;
    *(half4*)(Vext + ((size_t)(b0 + frow) * KEXT + orow) * HDIM + k0) = hv;
  }
}

// ---------------------------------------------------------------------------
// Kernel B: tA[b][h][k] = tanh(Vext[b][k] @ Wa^T + bWa)  (fp16, k-major)
//           tq[b][p][h] = tanh(Q_p @ Ua^T + bUa)         (fp16)
// ---------------------------------------------------------------------------
__global__ __launch_bounds__(256, 1)
void proj_kernel(const _Float16* __restrict__ Vext, const _Float16* __restrict__ Hfin,
                 const float* __restrict__ Wa, const float* __restrict__ bWa,
                 const float* __restrict__ Ua, const float* __restrict__ bUa,
                 _Float16* __restrict__ tA, _Float16* __restrict__ tq)
{
  const int b = blockIdx.x;
  const int tid = threadIdx.x;
  const int wave = tid >> 6, lane = tid & 63;
  const int fr = lane & 15, fg = lane >> 4;
  __shared__ _Float16 tile[4][128][24];

  half8 bf[8][4];
  float bias_r[8];
#pragma unroll
  for (int nt = 0; nt < 8; ++nt) {
    const int ho = nt * 16 + fr;
    bias_r[nt] = bWa[ho];
#pragma unroll
    for (int kf = 0; kf < 4; ++kf)
      bf[nt][kf] = load8f(Wa + ho * HDIM + kf * 32 + fg * 8);
  }

  for (int r = 0; r < 10; ++r) {
    const int mt = r * 4 + wave;
    int row = mt * 16 + fr;
    if (row > KEXT - 1) row = KEXT - 1;
    const _Float16* src = Vext + ((size_t)b * KEXT + row) * HDIM;
    half8 af[4];
#pragma unroll
    for (int kf = 0; kf < 4; ++kf) af[kf] = *(const half8*)(src + kf * 32 + fg * 8);
#pragma unroll
    for (int nt = 0; nt < 8; ++nt) {
      f32x4 a = {0.f, 0.f, 0.f, 0.f};
#pragma unroll
      for (int kf = 0; kf < 4; ++kf)
        a = __builtin_amdgcn_mfma_f32_16x16x32_f16(af[kf], bf[nt][kf], a, 0, 0, 0);
#pragma unroll
      for (int j = 0; j < 4; ++j)
        tile[wave][nt * 16 + fr][fg * 4 + j] = (_Float16)fast_tanh(a[j] + bias_r[nt]);
    }
    __syncthreads();
    for (int it = tid; it < 4 * 128; it += 256) {
      const int w2 = it >> 7, ho = it & 127;
      const half8 v0 = *(const half8*)&tile[w2][ho][0];
      const half8 v1 = *(const half8*)&tile[w2][ho][8];
      _Float16* dst = tA + ((size_t)b * HDIM + ho) * KPAD + (r * 4 + w2) * 16;
      *(half8*)dst = v0;
      *(half8*)(dst + 8) = v1;
    }
    __syncthreads();
  }

#pragma unroll
  for (int nt = 0; nt < 8; ++nt) {
    const int ho = nt * 16 + fr;
    bias_r[nt] = bUa[ho];
#pragma unroll
    for (int kf = 0; kf < 4; ++kf)
      bf[nt][kf] = load8f(Ua + ho * HDIM + kf * 32 + fg * 8);
  }
  for (int r = 0; r < 2; ++r) {
    const int mt = r * 4 + wave;
    const int prow = mt * 16 + fr;
    const _Float16* src = (prow == 0)
        ? (Hfin + (size_t)b * HDIM)
        : (Vext + ((size_t)b * KEXT + 511 + prow) * HDIM);
    half8 af[4];
#pragma unroll
    for (int kf = 0; kf < 4; ++kf) af[kf] = *(const half8*)(src + kf * 32 + fg * 8);
#pragma unroll
    for (int nt = 0; nt < 8; ++nt) {
      f32x4 a = {0.f, 0.f, 0.f, 0.f};
#pragma unroll
      for (int kf = 0; kf < 4; ++kf)
        a = __builtin_amdgcn_mfma_f32_16x16x32_f16(af[kf], bf[nt][kf], a, 0, 0, 0);
#pragma unroll
      for (int j = 0; j < 4; ++j) {
        const int pq = mt * 16 + fg * 4 + j;
        tq[((size_t)b * LOUT + pq) * HDIM + nt * 16 + fr] = (_Float16)fast_tanh(a[j] + bias_r[nt]);
      }
    }
  }
}

// ---------------------------------------------------------------------------
// Kernel C: attention. grid (B, 8 p-blocks of 16), 512 thr, 2 queries/wave.
// LDS 64.5 KiB -> 2 WGs/CU. fp16 scores; masked chunks skipped exactly.
// ---------------------------------------------------------------------------
__global__ __launch_bounds__(512)
void attn_kernel(const _Float16* __restrict__ Vext,
                 const _Float16* __restrict__ tA,
                 const _Float16* __restrict__ tq,
                 const float* __restrict__ Va,
                 const int* __restrict__ lengths,
                 const float* __restrict__ fc1w, const float* __restrict__ fc1b,
                 const float* __restrict__ fc2w, const float* __restrict__ fc2b,
                 float* __restrict__ out)
{
  const int b = blockIdx.x;
  const int p0 = blockIdx.y * 16;
  const int tid = threadIdx.x, wv = tid >> 6, lane = tid & 63;

  __shared__ __align__(16) char stg_raw[128 * 136 * 2];  // 34 KiB staging / f1+ctx alias
  __shared__ __align__(16) char sc_raw[16 * 648 * 2];    // 20.7 KiB fp16 scores / ctx alias
  __shared__ float qs[16][132];
  __shared__ float vas[HDIM];
  auto stg = (_Float16(*)[136])stg_raw;
  auto sc  = (_Float16(*)[648])sc_raw;

  for (int it = tid; it < 16 * HDIM; it += 512)
    qs[it >> 7][it & 127] = (float)tq[((size_t)b * LOUT + p0 + (it >> 7)) * HDIM + (it & 127)];
  if (tid < HDIM) vas[tid] = Va[tid];
  const int len = clampT(lengths[b]);
  const float fb   = (lane < 32) ? fc1b[lane] : 0.f;
  const float w2a  = (lane < 32) ? fc2w[lane] : 0.f;
  const float w2b  = (lane < 32) ? fc2w[32 + lane] : 0.f;
  const float f2b0 = fc2b[0], f2b1 = fc2b[1];
  const _Float16 NEGINF = (_Float16)(-__builtin_inff());
  __syncthreads();

  // ---- scores (5 chunks of 128 keys) ----
  for (int kc = 0; kc < 5; ++kc) {
    const int ck0 = kc * 128;
    const bool alive = (ck0 < T) ? ((ck0 == 0) || (ck0 < len))
                                 : ((ck0 - T) < p0 + 15);
    if (alive) {
      __syncthreads();
      for (int it = tid; it < 2048; it += 512) {
        const int hh = it >> 4, ks = it & 15;
        *(half8*)&stg[hh][ks * 8] =
            *(const half8*)(tA + ((size_t)b * HDIM + hh) * KPAD + ck0 + ks * 8);
      }
      __syncthreads();
    }
#pragma unroll
    for (int pp = 0; pp < 2; ++pp) {
      const int prow = wv * 2 + pp;
      const int p = p0 + prow;
      const int k0 = ck0 + lane * 2, k1 = k0 + 1;
      bool anyv;
      if (ck0 < T) {
        const int kmax = min(ck0 + 127, len - 1);
        anyv = (ck0 == 0) || ((ck0 < len) && (kmax > p));
      } else {
        anyv = (ck0 - T) < p;
      }
      if (!anyv) {
        half2t z; z[0] = NEGINF; z[1] = NEGINF;
        *(half2t*)&sc[prow][k0] = z;
        continue;
      }
      float acc0 = 0.f, acc1 = 0.f;
#pragma unroll 4
      for (int h = 0; h < HDIM; ++h) {
        const half2t a = *(const half2t*)&stg[h][lane * 2];
        const float tqv = qs[prow][h];
        const float va = vas[h];
        const float a0 = (float)a[0], a1 = (float)a[1];
        const float t0 = (a0 + tqv) * __builtin_amdgcn_rcpf(fmaf(a0, tqv, 1.f));
        const float t1 = (a1 + tqv) * __builtin_amdgcn_rcpf(fmaf(a1, tqv, 1.f));
        acc0 = fmaf(va, t0, acc0);
        acc1 = fmaf(va, t1, acc1);
      }
      const bool v0 = (k0 < T) ? ((k0 < len) && (k0 == 0 || k0 > p)) : ((k0 - T) < p);
      const bool v1 = (k1 < T) ? ((k1 < len) && (k1 > p)) : ((k1 - T) < p);
      half2t sv;
      sv[0] = v0 ? (_Float16)acc0 : NEGINF;
      sv[1] = v1 ? (_Float16)acc1 : NEGINF;
      *(half2t*)&sc[prow][k0] = sv;
    }
  }

  // ---- softmax (wave-local rows, no barrier needed) ----
  float inv[2];
#pragma unroll
  for (int pp = 0; pp < 2; ++pp) {
    const int prow = wv * 2 + pp;
    float m = -__builtin_inff();
    for (int k = lane; k < KPAD; k += 64) m = fmaxf(m, (float)sc[prow][k]);
#pragma unroll
    for (int off = 32; off; off >>= 1) m = fmaxf(m, __shfl_xor(m, off, 64));
    float ssum = 0.f;
    for (int k = lane; k < KPAD; k += 64) {
      const float e = __builtin_amdgcn_exp2f(((float)sc[prow][k] - m) * 1.44269504f);
      sc[prow][k] = (_Float16)e;
      ssum += e;
    }
#pragma unroll
    for (int off = 32; off; off >>= 1) ssum += __shfl_xor(ssum, off, 64);
    inv[pp] = __builtin_amdgcn_rcpf(ssum);
  }

  // ---- context (5 chunks of 128 keys) ----
  float ca[2] = {0.f, 0.f}, cb[2] = {0.f, 0.f};
  for (int vc = 0; vc < 5; ++vc) {
    const int ck0 = vc * 128;
    const bool alive = (ck0 < T) ? ((ck0 == 0) || (ck0 < len))
                                 : ((ck0 - T) < p0 + 15);
    if (!alive) continue;
    __syncthreads();
    for (int it = tid; it < 2048; it += 512) {
      const int kk = it >> 4, hs = it & 15;
      const int krow = min(ck0 + kk, KEXT - 1);
      *(half8*)&stg[kk][hs * 8] =
          *(const half8*)(Vext + ((size_t)b * KEXT + krow) * HDIM + hs * 8);
    }
    __syncthreads();
#pragma unroll
    for (int pp = 0; pp < 2; ++pp) {
      const int prow = wv * 2 + pp;
      const int p = p0 + prow;
      bool anyv;
      if (ck0 < T) {
        const int kmax = min(ck0 + 127, len - 1);
        anyv = (ck0 == 0) || ((ck0 < len) && (kmax > p));
      } else {
        anyv = (ck0 - T) < p;
      }
      if (!anyv) continue;
      float a0 = ca[pp], a1 = cb[pp];
#pragma unroll 4
      for (int kk = 0; kk < 128; ++kk) {
        const float wgt = (float)sc[prow][ck0 + kk];
        const half2t v = *(const half2t*)&stg[kk][lane * 2];
        a0 = fmaf(wgt, (float)v[0], a0);
        a1 = fmaf(wgt, (float)v[1], a1);
      }
      ca[pp] = a0; cb[pp] = a1;
    }
  }
  __syncthreads();   // protect sc->ctx and stg->f1 aliasing

  auto ctxs = (float(*)[128])sc_raw;
  auto f1   = (_Float16(*)[132])stg_raw;
#pragma unroll
  for (int pp = 0; pp < 2; ++pp) {
    const int prow = wv * 2 + pp;
    float2 cv; cv.x = ca[pp] * inv[pp]; cv.y = cb[pp] * inv[pp];
    *(float2*)&ctxs[prow][lane * 2] = cv;
  }
  for (int it = tid; it < 32 * HDIM; it += 512)
    f1[it >> 7][it & 127] = (_Float16)fc1w[it];
  __syncthreads();

  // ---- head: relu(ctx@fc1^T+b1)@fc2^T+b2, fc2 via shuffle reduce ----
#pragma unroll
  for (int pp = 0; pp < 2; ++pp) {
    const int prow = wv * 2 + pp;
    float r = 0.f;
    if (lane < 32) {
      float a = fb;
      for (int h = 0; h < HDIM; ++h)
        a = fmaf(ctxs[prow][h], (float)f1[lane][h], a);
      r = fmaxf(a, 0.f);
    }
    float s0 = r * w2a, s1 = r * w2b;
#pragma unroll
    for (int off = 16; off; off >>= 1) {
      s0 += __shfl_xor(s0, off, 64);
      s1 += __shfl_xor(s1, off, 64);
    }
    if (lane == 0) {
      float* o = out + ((size_t)b * LOUT + p0 + prow) * 2;
      o[0] = s0 + f2b0;
      o[1] = s1 + f2b1;
    }
  }
}

// ---------------------------------------------------------------------------
extern "C" void kernel_launch(void* const* d_in, const int* in_sizes, int n_in,
                              void* d_out, int out_size, void* d_ws, size_t ws_size,
                              hipStream_t stream)
{
  const float* x     = (const float*)d_in[0];
  const float* y     = (const float*)d_in[1];
  const int* lengths = (const int*)d_in[3];
  const float* Wih0  = (const float*)d_in[4];
  const float* Whh0  = (const float*)d_in[5];
  const float* bih0  = (const float*)d_in[6];
  const float* bhh0  = (const float*)d_in[7];
  const float* Wih1  = (const float*)d_in[8];
  const float* Whh1  = (const float*)d_in[9];
  const float* bih1  = (const float*)d_in[10];
  const float* bhh1  = (const float*)d_in[11];
  const float* Wa    = (const float*)d_in[12];
  const float* bWa   = (const float*)d_in[13];
  const float* Ua    = (const float*)d_in[14];
  const float* bUa   = (const float*)d_in[15];
  const float* Va    = (const float*)d_in[16];
  const float* fc1w  = (const float*)d_in[18];
  const float* fc1b  = (const float*)d_in[19];
  const float* fc2w  = (const float*)d_in[20];
  const float* fc2b  = (const float*)d_in[21];

  char* wsp = (char*)d_ws;
  _Float16* Vext = (_Float16*)(wsp);              // 256*639*128*2  = 41,877,504
  _Float16* Hfin = (_Float16*)(wsp + 41877504);   // 256*128*2      =     65,536
  _Float16* tA   = (_Float16*)(wsp + 41943040);   // 256*128*640*2  = 41,943,040
  _Float16* tq   = (_Float16*)(wsp + 83886080);   // 256*128*128*2  =  8,388,608
  _Float16* W16_0 = (_Float16*)(wsp + 92274688);  // 512*128*2      =    131,072
  _Float16* W16_1 = (_Float16*)(wsp + 92405760);  // 512*128*2      =    131,072
  (void)in_sizes; (void)n_in; (void)out_size; (void)ws_size;

  prep_kernel<<<64, 256, 0, stream>>>(Whh0, Whh1, W16_0, W16_1);
  lstm_kernel<<<16, 512, 0, stream>>>(x, y, lengths, Wih0, W16_0, bih0, bhh0,
                                      Wih1, W16_1, bih1, bhh1, Vext, Hfin);
  proj_kernel<<<256, 256, 0, stream>>>(Vext, Hfin, Wa, bWa, Ua, bUa, tA, tq);
  attn_kernel<<<dim3(256, 8), 512, 0, stream>>>(Vext, tA, tq, Va, lengths,
                                                fc1w, fc1b, fc2w, fc2b,
                                                (float*)d_out);
}

// Round 8
// 1744.098 us; speedup vs baseline: 2.9089x; 1.6100x over previous
//
#include <hip/hip_runtime.h>

#define T 512
#define HDIM 128
#define LOUT 128
#define KEXT 639
#define KPAD 640
#define BM 4

typedef _Float16 half8 __attribute__((ext_vector_type(8)));
typedef _Float16 half4 __attribute__((ext_vector_type(4)));
typedef _Float16 half2t __attribute__((ext_vector_type(2)));
typedef float f32x4 __attribute__((ext_vector_type(4)));
typedef unsigned int u32x4 __attribute__((ext_vector_type(4)));

__device__ __forceinline__ int clampT(int v) { return v < 0 ? 0 : (v > T ? T : v); }

__device__ __forceinline__ half8 load8f(const float* p) {
  float4 q0 = *(const float4*)p;
  float4 q1 = *(const float4*)(p + 4);
  half8 v;
  v[0] = (_Float16)q0.x; v[1] = (_Float16)q0.y; v[2] = (_Float16)q0.z; v[3] = (_Float16)q0.w;
  v[4] = (_Float16)q1.x; v[5] = (_Float16)q1.y; v[6] = (_Float16)q1.z; v[7] = (_Float16)q1.w;
  return v;
}

// volatile 16B load: executed exactly once -> value must stay resident (VGPR/AGPR)
__device__ __forceinline__ half8 load8h_once(const _Float16* p) {
  u32x4 raw = *(volatile const u32x4*)p;
  return __builtin_bit_cast(half8, raw);
}

// merged-denominator LSTM cell
__device__ __forceinline__ void cell_up(float gi, float gf, float gg, float go,
                                        float& cr, _Float16& hh, bool v) {
  const float A = 1.44269504f, B2 = 2.88539008f;
  const float Fi = __builtin_amdgcn_exp2f(-gi * A);
  const float Ff = __builtin_amdgcn_exp2f(-gf * A);
  const float Fo = __builtin_amdgcn_exp2f(-go * A);
  const float Eg = __builtin_amdgcn_exp2f(gg * B2);
  const float it = (Eg - 1.f) * __builtin_amdgcn_rcpf((1.f + Fi) * (1.f + Eg));
  const float cn = cr * __builtin_amdgcn_rcpf(1.f + Ff) + it;
  const float ec = __builtin_amdgcn_exp2f(-B2 * __builtin_fabsf(cn));
  const float h  = __builtin_copysignf(
      (1.f - ec) * __builtin_amdgcn_rcpf((1.f + Fo) * (1.f + ec)), cn);
  if (v) { cr = cn; hh = (_Float16)h; }
}

__device__ __forceinline__ float fast_tanh(float x) {
  float ax = __builtin_fabsf(x);
  float e = __builtin_amdgcn_exp2f(ax * -2.88539008f);
  float t = (1.f - e) * __builtin_amdgcn_rcpf(1.f + e);
  return __builtin_copysignf(t, x);
}

// ---------------------------------------------------------------------------
// Kernel P: one-time fp32 -> fp16 conversion of Whh0 / Wih1 / Whh1
// ---------------------------------------------------------------------------
__global__ __launch_bounds__(256)
void prep_kernel(const float* __restrict__ Whh0, const float* __restrict__ Wih1,
                 const float* __restrict__ Whh1,
                 _Float16* __restrict__ A, _Float16* __restrict__ B,
                 _Float16* __restrict__ C)
{
  const int i = (blockIdx.x * 256 + threadIdx.x) * 4;   // 64 blocks -> 65536 elems
  float4 a = *(const float4*)(Whh0 + i);
  float4 b = *(const float4*)(Wih1 + i);
  float4 c = *(const float4*)(Whh1 + i);
  half4 ha = {(_Float16)a.x, (_Float16)a.y, (_Float16)a.z, (_Float16)a.w};
  half4 hb = {(_Float16)b.x, (_Float16)b.y, (_Float16)b.z, (_Float16)b.w};
  half4 hc = {(_Float16)c.x, (_Float16)c.y, (_Float16)c.z, (_Float16)c.w};
  *(half4*)(A + i) = ha;
  *(half4*)(B + i) = hb;
  *(half4*)(C + i) = hc;
}

// ---------------------------------------------------------------------------
// Kernel A: persistent 2-layer LSTM. 64 WGs x 512 threads, 4 batch rows/WG.
// All THREE recurrent matrices live in the unified VGPR/AGPR file (volatile
// fp16 loads, 192 reg-equiv). MFMA phase: wave w owns columns g*128+w*16+fr.
// Gates go through a small LDS buffer; cell phase: one cell/thread/layer.
// Two barriers per step. x/y fully staged in LDS (no per-step global loads).
// ---------------------------------------------------------------------------
__global__ __launch_bounds__(512) __attribute__((amdgpu_waves_per_eu(1, 2)))
void lstm_kernel(const float* __restrict__ x, const float* __restrict__ y,
                 const int* __restrict__ lengths,
                 const float* __restrict__ Wih0,
                 const _Float16* __restrict__ Wh0h,
                 const _Float16* __restrict__ Wi1h,
                 const _Float16* __restrict__ Wh1h,
                 const float* __restrict__ bih0, const float* __restrict__ bhh0,
                 const float* __restrict__ bih1, const float* __restrict__ bhh1,
                 _Float16* __restrict__ Vext, _Float16* __restrict__ Hfin)
{
  const int tid  = threadIdx.x;
  const int w    = tid >> 6;
  const int lane = tid & 63;
  const int fr   = lane & 15;
  const int fg   = lane >> 4;
  const int b0   = blockIdx.x * BM;
  const int u    = w * 16 + fr;                 // MFMA column-owner unit
  const int cb   = tid >> 7;                    // cell-phase batch row (0..3)
  const int cu   = tid & 127;                   // cell-phase unit
  const int hpos = (cu >> 3) * 128 + cb * 8 + (cu & 7);  // frag-order h slot

  __shared__ _Float16 h1buf[2048];              // frag-order h1 (rows 4-15 = 0)
  __shared__ _Float16 h2buf[2048];
  __shared__ float    gates2[8][516];           // rows 0-3: G1(s); 4-7: G0(s+1)
  __shared__ float    xlds[T][BM][3];
  __shared__ float    ylds[LOUT][BM][3];
  __shared__ float    w0lds[512][3];
  __shared__ float    b0lds[512], b1lds[512];
  __shared__ int      lens_s[BM];

  // ---- resident weight fragments (volatile: loaded exactly once) ----
  half8 wh0[4][4], wi1[4][4], wh1[4][4];
#pragma unroll
  for (int g = 0; g < 4; ++g) {
    const int n = g * 128 + u;
#pragma unroll
    for (int kf = 0; kf < 4; ++kf) {
      const int off = n * HDIM + kf * 32 + fg * 8;
      wh0[g][kf] = load8h_once(Wh0h + off);
      wi1[g][kf] = load8h_once(Wi1h + off);
      wh1[g][kf] = load8h_once(Wh1h + off);
    }
  }

  // ---- one-time staging ----
  if (tid < BM) lens_s[tid] = clampT(lengths[b0 + tid]);
  {
    const int n = tid;                          // exactly 512 threads
    b0lds[n] = bih0[n] + bhh0[n];
    b1lds[n] = bih1[n] + bhh1[n];
    w0lds[n][0] = Wih0[n * 3 + 0];
    w0lds[n][1] = Wih0[n * 3 + 1];
    w0lds[n][2] = Wih0[n * 3 + 2];
  }
  for (int it = tid; it < 2048; it += 512) {
    h1buf[it] = (_Float16)0.f; h2buf[it] = (_Float16)0.f;
  }
  for (int it = tid; it < BM * T * 3; it += 512) {
    const int b = it / (T * 3), r = it - b * (T * 3);
    xlds[r / 3][b][r % 3] = x[(size_t)(b0 + b) * T * 3 + r];
  }
  for (int it = tid; it < BM * LOUT * 3; it += 512) {
    const int b = it / (LOUT * 3), r = it - b * (LOUT * 3);
    ylds[r / 3][b][r % 3] = y[(size_t)(b0 + b) * LOUT * 3 + r];
  }
  __syncthreads();

  const int mylen_c = lens_s[cb];
  int maxlen = 0;
#pragma unroll
  for (int i = 0; i < BM; ++i) maxlen = max(maxlen, lens_s[i]);
  const int S = maxlen + LOUT - 1;

  // zero-fill encoder rows past this batch row's length (wave-uniform cb)
  for (int t = mylen_c; t < T; ++t)
    Vext[((size_t)(b0 + cb) * KEXT + t) * HDIM + cu] = (_Float16)0.f;

  // ---- prologue: cell0(0) (h1(-1)=0 -> gates = b0 + Wih0*x(0)) ----
  float c1r = 0.f, c2r = 0.f;
  _Float16 h1h = (_Float16)0.f, h2h = (_Float16)0.f;
  {
    const float x0 = xlds[0][cb][0], x1 = xlds[0][cb][1], x2 = xlds[0][cb][2];
    float gv[4];
#pragma unroll
    for (int g = 0; g < 4; ++g) {
      const int n = g * 128 + cu;
      gv[g] = b0lds[n] + x0 * w0lds[n][0] + x1 * w0lds[n][1] + x2 * w0lds[n][2];
    }
    cell_up(gv[0], gv[1], gv[2], gv[3], c1r, h1h, true);
    h1buf[hpos] = h1h;
  }
  __syncthreads();

  // ---- main loop: 2 barriers/step ----
  for (int s = 0; s < S; ++s) {
    // phase 1: A-fragments (conflict-free b128; h1(s), h2(s-1))
    half8 h1f[4], h2f[4];
#pragma unroll
    for (int kf = 0; kf < 4; ++kf) {
      h1f[kf] = *(const half8*)&h1buf[(kf * 4 + fg) * 128 + fr * 8];
      h2f[kf] = *(const half8*)&h2buf[(kf * 4 + fg) * 128 + fr * 8];
    }
    // phase 2a: G1(s) = h1(s)@Wih1^T + h2(s-1)@Whh1^T  -> gates2 rows 0-3
#pragma unroll
    for (int g = 0; g < 4; ++g) {
      f32x4 a = {0.f, 0.f, 0.f, 0.f};
#pragma unroll
      for (int kf = 0; kf < 4; ++kf)
        a = __builtin_amdgcn_mfma_f32_16x16x32_f16(h1f[kf], wi1[g][kf], a, 0, 0, 0);
#pragma unroll
      for (int kf = 0; kf < 4; ++kf)
        a = __builtin_amdgcn_mfma_f32_16x16x32_f16(h2f[kf], wh1[g][kf], a, 0, 0, 0);
      if (fg == 0) {
#pragma unroll
        for (int j = 0; j < 4; ++j) gates2[j][g * 128 + u] = a[j];
      }
    }
    // phase 2b: G0(s+1) = h1(s)@Whh0^T -> gates2 rows 4-7
#pragma unroll
    for (int g = 0; g < 4; ++g) {
      f32x4 a = {0.f, 0.f, 0.f, 0.f};
#pragma unroll
      for (int kf = 0; kf < 4; ++kf)
        a = __builtin_amdgcn_mfma_f32_16x16x32_f16(h1f[kf], wh0[g][kf], a, 0, 0, 0);
      if (fg == 0) {
#pragma unroll
        for (int j = 0; j < 4; ++j) gates2[4 + j][g * 128 + u] = a[j];
      }
    }
    __syncthreads();                            // BAR-1: gates ready

    // phase 4a: cell1(s) -> h2(s), Vext/Hfin store
    {
      float gv[4];
#pragma unroll
      for (int g = 0; g < 4; ++g) {
        const int n = g * 128 + cu;
        gv[g] = gates2[cb][n] + b1lds[n];
      }
      const bool v1 = (s >= maxlen) || (s < mylen_c);
      cell_up(gv[0], gv[1], gv[2], gv[3], c2r, h2h, v1);
      h2buf[hpos] = h2h;
      if (v1) {
        const int orow = (s < maxlen) ? s : (T + s - maxlen);
        Vext[((size_t)(b0 + cb) * KEXT + orow) * HDIM + cu] = h2h;
      }
      if (s == maxlen - 1)
        Hfin[(size_t)(b0 + cb) * HDIM + cu] = h2h;
    }
    // phase 4b: cell0(s+1) -> h1(s+1)
    {
      const int k = s + 1;
      const float* xp = (k < maxlen) ? &xlds[k][cb][0] : &ylds[k - maxlen][cb][0];
      const float x0 = xp[0], x1 = xp[1], x2 = xp[2];
      float gv[4];
#pragma unroll
      for (int g = 0; g < 4; ++g) {
        const int n = g * 128 + cu;
        gv[g] = gates2[4 + cb][n] + b0lds[n]
              + x0 * w0lds[n][0] + x1 * w0lds[n][1] + x2 * w0lds[n][2];
      }
      const bool v0 = (k >= maxlen) || (k < mylen_c);
      cell_up(gv[0], gv[1], gv[2], gv[3], c1r, h1h, v0);
      h1buf[hpos] = h1h;
    }
    __syncthreads();                            // BAR-2: h ready for next step
  }
}

// ---------------------------------------------------------------------------
// Kernel B: tA[b][h][k] = tanh(Vext[b][k] @ Wa^T + bWa)  (fp16, k-major)
//           tq[b][p][h] = tanh(Q_p @ Ua^T + bUa)         (fp16)
// ---------------------------------------------------------------------------
__global__ __launch_bounds__(256, 1)
void proj_kernel(const _Float16* __restrict__ Vext, const _Float16* __restrict__ Hfin,
                 const float* __restrict__ Wa, const float* __restrict__ bWa,
                 const float* __restrict__ Ua, const float* __restrict__ bUa,
                 _Float16* __restrict__ tA, _Float16* __restrict__ tq)
{
  const int b = blockIdx.x;
  const int tid = threadIdx.x;
  const int wave = tid >> 6, lane = tid & 63;
  const int fr = lane & 15, fg = lane >> 4;
  __shared__ _Float16 tile[4][128][24];

  half8 bf[8][4];
  float bias_r[8];
#pragma unroll
  for (int nt = 0; nt < 8; ++nt) {
    const int ho = nt * 16 + fr;
    bias_r[nt] = bWa[ho];
#pragma unroll
    for (int kf = 0; kf < 4; ++kf)
      bf[nt][kf] = load8f(Wa + ho * HDIM + kf * 32 + fg * 8);
  }

  for (int r = 0; r < 10; ++r) {
    const int mt = r * 4 + wave;
    int row = mt * 16 + fr;
    if (row > KEXT - 1) row = KEXT - 1;
    const _Float16* src = Vext + ((size_t)b * KEXT + row) * HDIM;
    half8 af[4];
#pragma unroll
    for (int kf = 0; kf < 4; ++kf) af[kf] = *(const half8*)(src + kf * 32 + fg * 8);
#pragma unroll
    for (int nt = 0; nt < 8; ++nt) {
      f32x4 a = {0.f, 0.f, 0.f, 0.f};
#pragma unroll
      for (int kf = 0; kf < 4; ++kf)
        a = __builtin_amdgcn_mfma_f32_16x16x32_f16(af[kf], bf[nt][kf], a, 0, 0, 0);
#pragma unroll
      for (int j = 0; j < 4; ++j)
        tile[wave][nt * 16 + fr][fg * 4 + j] = (_Float16)fast_tanh(a[j] + bias_r[nt]);
    }
    __syncthreads();
    for (int it = tid; it < 4 * 128; it += 256) {
      const int w2 = it >> 7, ho = it & 127;
      const half8 v0 = *(const half8*)&tile[w2][ho][0];
      const half8 v1 = *(const half8*)&tile[w2][ho][8];
      _Float16* dst = tA + ((size_t)b * HDIM + ho) * KPAD + (r * 4 + w2) * 16;
      *(half8*)dst = v0;
      *(half8*)(dst + 8) = v1;
    }
    __syncthreads();
  }

#pragma unroll
  for (int nt = 0; nt < 8; ++nt) {
    const int ho = nt * 16 + fr;
    bias_r[nt] = bUa[ho];
#pragma unroll
    for (int kf = 0; kf < 4; ++kf)
      bf[nt][kf] = load8f(Ua + ho * HDIM + kf * 32 + fg * 8);
  }
  for (int r = 0; r < 2; ++r) {
    const int mt = r * 4 + wave;
    const int prow = mt * 16 + fr;
    const _Float16* src = (prow == 0)
        ? (Hfin + (size_t)b * HDIM)
        : (Vext + ((size_t)b * KEXT + 511 + prow) * HDIM);
    half8 af[4];
#pragma unroll
    for (int kf = 0; kf < 4; ++kf) af[kf] = *(const half8*)(src + kf * 32 + fg * 8);
#pragma unroll
    for (int nt = 0; nt < 8; ++nt) {
      f32x4 a = {0.f, 0.f, 0.f, 0.f};
#pragma unroll
      for (int kf = 0; kf < 4; ++kf)
        a = __builtin_amdgcn_mfma_f32_16x16x32_f16(af[kf], bf[nt][kf], a, 0, 0, 0);
#pragma unroll
      for (int j = 0; j < 4; ++j) {
        const int pq = mt * 16 + fg * 4 + j;
        tq[((size_t)b * LOUT + pq) * HDIM + nt * 16 + fr] = (_Float16)fast_tanh(a[j] + bias_r[nt]);
      }
    }
  }
}

// ---------------------------------------------------------------------------
// Kernel C: attention. grid (B, 8 p-blocks of 16), 512 thr, 2 queries/wave.
// ---------------------------------------------------------------------------
__global__ __launch_bounds__(512)
void attn_kernel(const _Float16* __restrict__ Vext,
                 const _Float16* __restrict__ tA,
                 const _Float16* __restrict__ tq,
                 const float* __restrict__ Va,
                 const int* __restrict__ lengths,
                 const float* __restrict__ fc1w, const float* __restrict__ fc1b,
                 const float* __restrict__ fc2w, const float* __restrict__ fc2b,
                 float* __restrict__ out)
{
  const int b = blockIdx.x;
  const int p0 = blockIdx.y * 16;
  const int tid = threadIdx.x, wv = tid >> 6, lane = tid & 63;

  __shared__ __align__(16) char stg_raw[128 * 136 * 2];
  __shared__ __align__(16) char sc_raw[16 * 648 * 2];
  __shared__ float qs[16][132];
  __shared__ float vas[HDIM];
  auto stg = (_Float16(*)[136])stg_raw;
  auto sc  = (_Float16(*)[648])sc_raw;

  for (int it = tid; it < 16 * HDIM; it += 512)
    qs[it >> 7][it & 127] = (float)tq[((size_t)b * LOUT + p0 + (it >> 7)) * HDIM + (it & 127)];
  if (tid < HDIM) vas[tid] = Va[tid];
  const int len = clampT(lengths[b]);
  const float fb   = (lane < 32) ? fc1b[lane] : 0.f;
  const float w2a  = (lane < 32) ? fc2w[lane] : 0.f;
  const float w2b  = (lane < 32) ? fc2w[32 + lane] : 0.f;
  const float f2b0 = fc2b[0], f2b1 = fc2b[1];
  const _Float16 NEGINF = (_Float16)(-__builtin_inff());
  __syncthreads();

  for (int kc = 0; kc < 5; ++kc) {
    const int ck0 = kc * 128;
    const bool alive = (ck0 < T) ? ((ck0 == 0) || (ck0 < len))
                                 : ((ck0 - T) < p0 + 15);
    if (alive) {
      __syncthreads();
      for (int it = tid; it < 2048; it += 512) {
        const int hh = it >> 4, ks = it & 15;
        *(half8*)&stg[hh][ks * 8] =
            *(const half8*)(tA + ((size_t)b * HDIM + hh) * KPAD + ck0 + ks * 8);
      }
      __syncthreads();
    }
#pragma unroll
    for (int pp = 0; pp < 2; ++pp) {
      const int prow = wv * 2 + pp;
      const int p = p0 + prow;
      const int k0 = ck0 + lane * 2, k1 = k0 + 1;
      bool anyv;
      if (ck0 < T) {
        const int kmax = min(ck0 + 127, len - 1);
        anyv = (ck0 == 0) || ((ck0 < len) && (kmax > p));
      } else {
        anyv = (ck0 - T) < p;
      }
      if (!anyv) {
        half2t z; z[0] = NEGINF; z[1] = NEGINF;
        *(half2t*)&sc[prow][k0] = z;
        continue;
      }
      float acc0 = 0.f, acc1 = 0.f;
#pragma unroll 4
      for (int h = 0; h < HDIM; ++h) {
        const half2t a = *(const half2t*)&stg[h][lane * 2];
        const float tqv = qs[prow][h];
        const float va = vas[h];
        const float a0 = (float)a[0], a1 = (float)a[1];
        const float t0 = (a0 + tqv) * __builtin_amdgcn_rcpf(fmaf(a0, tqv, 1.f));
        const float t1 = (a1 + tqv) * __builtin_amdgcn_rcpf(fmaf(a1, tqv, 1.f));
        acc0 = fmaf(va, t0, acc0);
        acc1 = fmaf(va, t1, acc1);
      }
      const bool v0 = (k0 < T) ? ((k0 < len) && (k0 == 0 || k0 > p)) : ((k0 - T) < p);
      const bool v1 = (k1 < T) ? ((k1 < len) && (k1 > p)) : ((k1 - T) < p);
      half2t sv;
      sv[0] = v0 ? (_Float16)acc0 : NEGINF;
      sv[1] = v1 ? (_Float16)acc1 : NEGINF;
      *(half2t*)&sc[prow][k0] = sv;
    }
  }

  float inv[2];
#pragma unroll
  for (int pp = 0; pp < 2; ++pp) {
    const int prow = wv * 2 + pp;
    float m = -__builtin_inff();
    for (int k = lane; k < KPAD; k += 64) m = fmaxf(m, (float)sc[prow][k]);
#pragma unroll
    for (int off = 32; off; off >>= 1) m = fmaxf(m, __shfl_xor(m, off, 64));
    float ssum = 0.f;
    for (int k = lane; k < KPAD; k += 64) {
      const float e = __builtin_amdgcn_exp2f(((float)sc[prow][k] - m) * 1.44269504f);
      sc[prow][k] = (_Float16)e;
      ssum += e;
    }
#pragma unroll
    for (int off = 32; off; off >>= 1) ssum += __shfl_xor(ssum, off, 64);
    inv[pp] = __builtin_amdgcn_rcpf(ssum);
  }

  float ca[2] = {0.f, 0.f}, cb[2] = {0.f, 0.f};
  for (int vc = 0; vc < 5; ++vc) {
    const int ck0 = vc * 128;
    const bool alive = (ck0 < T) ? ((ck0 == 0) || (ck0 < len))
                                 : ((ck0 - T) < p0 + 15);
    if (!alive) continue;
    __syncthreads();
    for (int it = tid; it < 2048; it += 512) {
      const int kk = it >> 4, hs = it & 15;
      const int krow = min(ck0 + kk, KEXT - 1);
      *(half8*)&stg[kk][hs * 8] =
          *(const half8*)(Vext + ((size_t)b * KEXT + krow) * HDIM + hs * 8);
    }
    __syncthreads();
#pragma unroll
    for (int pp = 0; pp < 2; ++pp) {
      const int prow = wv * 2 + pp;
      const int p = p0 + prow;
      bool anyv;
      if (ck0 < T) {
        const int kmax = min(ck0 + 127, len - 1);
        anyv = (ck0 == 0) || ((ck0 < len) && (kmax > p));
      } else {
        anyv = (ck0 - T) < p;
      }
      if (!anyv) continue;
      float a0 = ca[pp], a1 = cb[pp];
#pragma unroll 4
      for (int kk = 0; kk < 128; ++kk) {
        const float wgt = (float)sc[prow][ck0 + kk];
        const half2t v = *(const half2t*)&stg[kk][lane * 2];
        a0 = fmaf(wgt, (float)v[0], a0);
        a1 = fmaf(wgt, (float)v[1], a1);
      }
      ca[pp] = a0; cb[pp] = a1;
    }
  }
  __syncthreads();

  auto ctxs = (float(*)[128])sc_raw;
  auto f1   = (_Float16(*)[132])stg_raw;
#pragma unroll
  for (int pp = 0; pp < 2; ++pp) {
    const int prow = wv * 2 + pp;
    float2 cv; cv.x = ca[pp] * inv[pp]; cv.y = cb[pp] * inv[pp];
    *(float2*)&ctxs[prow][lane * 2] = cv;
  }
  for (int it = tid; it < 32 * HDIM; it += 512)
    f1[it >> 7][it & 127] = (_Float16)fc1w[it];
  __syncthreads();

#pragma unroll
  for (int pp = 0; pp < 2; ++pp) {
    const int prow = wv * 2 + pp;
    float r = 0.f;
    if (lane < 32) {
      float a = fb;
      for (int h = 0; h < HDIM; ++h)
        a = fmaf(ctxs[prow][h], (float)f1[lane][h], a);
      r = fmaxf(a, 0.f);
    }
    float s0 = r * w2a, s1 = r * w2b;
#pragma unroll
    for (int off = 16; off; off >>= 1) {
      s0 += __shfl_xor(s0, off, 64);
      s1 += __shfl_xor(s1, off, 64);
    }
    if (lane == 0) {
      float* o = out + ((size_t)b * LOUT + p0 + prow) * 2;
      o[0] = s0 + f2b0;
      o[1] = s1 + f2b1;
    }
  }
}

// ---------------------------------------------------------------------------
extern "C" void kernel_launch(void* const* d_in, const int* in_sizes, int n_in,
                              void* d_out, int out_size, void* d_ws, size_t ws_size,
                              hipStream_t stream)
{
  const float* x     = (const float*)d_in[0];
  const float* y     = (const float*)d_in[1];
  const int* lengths = (const int*)d_in[3];
  const float* Wih0  = (const float*)d_in[4];
  const float* Whh0  = (const float*)d_in[5];
  const float* bih0  = (const float*)d_in[6];
  const float* bhh0  = (const float*)d_in[7];
  const float* Wih1  = (const float*)d_in[8];
  const float* Whh1  = (const float*)d_in[9];
  const float* bih1  = (const float*)d_in[10];
  const float* bhh1  = (const float*)d_in[11];
  const float* Wa    = (const float*)d_in[12];
  const float* bWa   = (const float*)d_in[13];
  const float* Ua    = (const float*)d_in[14];
  const float* bUa   = (const float*)d_in[15];
  const float* Va    = (const float*)d_in[16];
  const float* fc1w  = (const float*)d_in[18];
  const float* fc1b  = (const float*)d_in[19];
  const float* fc2w  = (const float*)d_in[20];
  const float* fc2b  = (const float*)d_in[21];

  char* wsp = (char*)d_ws;
  _Float16* Vext  = (_Float16*)(wsp);              // 256*639*128*2  = 41,877,504
  _Float16* Hfin  = (_Float16*)(wsp + 41877504);   // 256*128*2      =     65,536
  _Float16* tA    = (_Float16*)(wsp + 41943040);   // 256*128*640*2  = 41,943,040
  _Float16* tq    = (_Float16*)(wsp + 83886080);   // 256*128*128*2  =  8,388,608
  _Float16* W16_0 = (_Float16*)(wsp + 92274688);   // 512*128*2
  _Float16* W16_i = (_Float16*)(wsp + 92405760);   // 512*128*2
  _Float16* W16_1 = (_Float16*)(wsp + 92536832);   // 512*128*2
  (void)in_sizes; (void)n_in; (void)out_size; (void)ws_size;

  prep_kernel<<<64, 256, 0, stream>>>(Whh0, Wih1, Whh1, W16_0, W16_i, W16_1);
  lstm_kernel<<<64, 512, 0, stream>>>(x, y, lengths, Wih0, W16_0, W16_i, W16_1,
                                      bih0, bhh0, bih1, bhh1, Vext, Hfin);
  proj_kernel<<<256, 256, 0, stream>>>(Vext, Hfin, Wa, bWa, Ua, bUa, tA, tq);
  attn_kernel<<<dim3(256, 8), 512, 0, stream>>>(Vext, tA, tq, Va, lengths,
                                                fc1w, fc1b, fc2w, fc2b,
                                                (float*)d_out);
}